// Round 13
// baseline (484.535 us; speedup 1.0000x reference)
//
#include <hip/hip_runtime.h>
#include <math.h>

namespace {

constexpr int B  = 2;
constexpr int N  = 1024;
constexpr int CF = 64;    // C_FEAT
constexpr int S  = 512;
constexpr int K  = 32;
constexpr int DM = 128;   // D_MODEL
constexpr int NH = 4;
constexpr int DH = 32;
constexpr int GC = 67;    // grouped channels = CF + 3
constexpr int DIN = 131;  // GC + CF
constexpr int DPAD = 132; // padded row for float4 LDS reads
constexpr int EPAD = 516; // S+4: keeps e rows 16B-aligned for float4 reads

constexpr int FPS_GRID = 1024;  // B fps blocks + calibrated DVFS burners

typedef float f2 __attribute__((ext_vector_type(2)));

__device__ inline float max3f(float a, float b, float c) { return fmaxf(fmaxf(a, b), c); }
__device__ inline unsigned min3u(unsigned a, unsigned b, unsigned c) { return min(min(a, b), c); }

// DPP helpers. Reduce-to-lane63 pattern: row_shr:1/2/4/8, row_bcast:15, row_bcast:31.
template <int CTRL>
__device__ inline float dpp_mov_f(float v) {
  // bound_ctrl=true: invalid lanes read 0 — valid identity for fmax of nonneg values.
  return __int_as_float(__builtin_amdgcn_update_dpp(0, __float_as_int(v), CTRL, 0xF, 0xF, true));
}
template <int CTRL>
__device__ inline unsigned dpp_mov_self_u(unsigned v) {
  // bound_ctrl=false with old=v: invalid lanes yield v — identity for min.
  return (unsigned)__builtin_amdgcn_update_dpp((int)v, (int)v, CTRL, 0xF, 0xF, false);
}

// ---------------- FPS (r10 config, priority 3) + calibrated burner blocks ----------------
// Blocks 0..B-1: verified FPS at wave priority 3 (shielded from issue
// contention). Blocks >= B: issue-bound burn of 4 independent FMA chains,
// ~300K cycles — 200us @1.5GHz / 125us @2.4GHz, i.e. ALWAYS shorter than the
// fps chain, so dispatch duration = fps time (clean A/B readout, fixes r11's
// confounded experiment). Deterministic, writes nothing, asm sink vs DCE.
__global__ void __launch_bounds__(64, 1)
fps_kernel(const float* __restrict__ xyz, int* __restrict__ fps_idx,
           float* __restrict__ new_xyz) {
  if (blockIdx.x >= B) {
    float a0 = 1.0f + (float)threadIdx.x * 1e-6f;
    float a1 = a0 + 0.5f, a2 = a0 + 0.25f, a3 = a0 + 0.75f;
    const float c = 1.0000001f;
    for (int it = 0; it < 9375; ++it) {
      #pragma unroll
      for (int u = 0; u < 4; ++u) {
        a0 = __builtin_fmaf(a0, c, 1e-7f);
        a1 = __builtin_fmaf(a1, c, 1e-7f);
        a2 = __builtin_fmaf(a2, c, 1e-7f);
        a3 = __builtin_fmaf(a3, c, 1e-7f);
      }
    }
    asm volatile("" :: "v"(a0), "v"(a1), "v"(a2), "v"(a3));
    return;
  }
  __builtin_amdgcn_s_setprio(3);
  const int b = blockIdx.x;
  const int lane = threadIdx.x;           // 64 threads = 1 wave
  __shared__ __align__(16) float4 pts4[N];
  __shared__ int farhist[S];
  for (int p = lane; p < N; p += 64) {
    pts4[p] = make_float4(xyz[b*N*3 + p*3+0], xyz[b*N*3 + p*3+1], xyz[b*N*3 + p*3+2], 0.0f);
  }
  __syncthreads();
  f2 X[8], Y[8], Z[8];
  float dist[16];
  #pragma unroll
  for (int j = 0; j < 8; ++j) {
    const float4 a = pts4[(2*j)*64 + lane];
    const float4 c = pts4[(2*j+1)*64 + lane];
    X[j] = f2{a.x, c.x}; Y[j] = f2{a.y, c.y}; Z[j] = f2{a.z, c.z};
  }
  #pragma unroll
  for (int k = 0; k < 16; ++k) dist[k] = 1e10f;
  int far = 0;
  for (int s = 0; s < S; ++s) {
    if (lane == 0) farhist[s] = far;
    const float4 c = pts4[far];
    const f2 cx = f2{c.x, c.x}, cy = f2{c.y, c.y}, cz = f2{c.z, c.z};
    #pragma unroll
    for (int j = 0; j < 8; ++j) {
      const f2 dx = X[j] - cx, dy = Y[j] - cy, dz = Z[j] - cz;
      const f2 q = dx*dx + dy*dy + dz*dz;    // same per-element expression as reference
      dist[2*j]   = fminf(dist[2*j],   q.x);
      dist[2*j+1] = fminf(dist[2*j+1], q.y);
    }
    // pass 1: lane-local max via max3 tree (7 ops, depth 3)
    const float l0 = max3f(dist[0],  dist[1],  dist[2]);
    const float l1 = max3f(dist[3],  dist[4],  dist[5]);
    const float l2 = max3f(dist[6],  dist[7],  dist[8]);
    const float l3 = max3f(dist[9],  dist[10], dist[11]);
    const float l4 = max3f(dist[12], dist[13], dist[14]);
    float mv = fmaxf(max3f(l0, l1, l2), max3f(l3, l4, dist[15]));
    // wave64 max via DPP, result valid in lane 63
    mv = fmaxf(mv, dpp_mov_f<0x111>(mv));
    mv = fmaxf(mv, dpp_mov_f<0x112>(mv));
    mv = fmaxf(mv, dpp_mov_f<0x114>(mv));
    mv = fmaxf(mv, dpp_mov_f<0x118>(mv));
    mv = fmaxf(mv, dpp_mov_f<0x142>(mv));
    mv = fmaxf(mv, dpp_mov_f<0x143>(mv));
    const float maxv = __int_as_float(__builtin_amdgcn_readlane(__float_as_int(mv), 63));
    // pass 2: min index among exact maxima (min3 tree)
    unsigned cnd[16];
    #pragma unroll
    for (int k = 0; k < 16; ++k) {
      cnd[k] = (dist[k] == maxv) ? (unsigned)(k*64 + lane) : 0xFFFFFFFFu;
    }
    const unsigned u0 = min3u(cnd[0],  cnd[1],  cnd[2]);
    const unsigned u1 = min3u(cnd[3],  cnd[4],  cnd[5]);
    const unsigned u2 = min3u(cnd[6],  cnd[7],  cnd[8]);
    const unsigned u3 = min3u(cnd[9],  cnd[10], cnd[11]);
    const unsigned u4 = min3u(cnd[12], cnd[13], cnd[14]);
    unsigned cand = min(min3u(u0, u1, u2), min3u(u3, u4, cnd[15]));
    cand = min(cand, dpp_mov_self_u<0x111>(cand));
    cand = min(cand, dpp_mov_self_u<0x112>(cand));
    cand = min(cand, dpp_mov_self_u<0x114>(cand));
    cand = min(cand, dpp_mov_self_u<0x118>(cand));
    cand = min(cand, dpp_mov_self_u<0x142>(cand));
    cand = min(cand, dpp_mov_self_u<0x143>(cand));
    far = __builtin_amdgcn_readlane((int)cand, 63);
  }
  __syncthreads();
  // epilogue: write fps_idx and new_xyz from history
  for (int s = lane; s < S; s += 64) {
    const int f = farhist[s];
    const float4 c = pts4[f];
    fps_idx[b*S+s] = f;
    new_xyz[(b*S+s)*3+0] = c.x;
    new_xyz[(b*S+s)*3+1] = c.y;
    new_xyz[(b*S+s)*3+2] = c.z;
  }
}

// ---------------- KNN (K=32 of N=1024), one wave per query ----------------
__global__ void knn_kernel(const float* __restrict__ xyz, const float* __restrict__ new_xyz,
                           int* __restrict__ knn_idx) {
  const int b = blockIdx.y;
  const int tid = threadIdx.x;            // 256
  const int wave = tid >> 6, lane = tid & 63;
  const int s = blockIdx.x * 4 + wave;
  __shared__ float pts[N*3];
  for (int i = tid; i < N*3; i += 256) pts[i] = xyz[b*N*3 + i];
  __syncthreads();
  const float qx = new_xyz[(b*S+s)*3+0], qy = new_xyz[(b*S+s)*3+1], qz = new_xyz[(b*S+s)*3+2];
  const float qn = qx*qx + qy*qy + qz*qz;
  float d[16];
  #pragma unroll
  for (int j = 0; j < 16; ++j) {
    const int p = j*64 + lane;
    const float px = pts[p*3+0], py = pts[p*3+1], pz = pts[p*3+2];
    const float dot = qx*px + qy*py + qz*pz;
    const float pn  = px*px + py*py + pz*pz;
    d[j] = (-2.0f*dot + qn) + pn;          // reference's expanded form + add order
  }
  unsigned mask = 0xFFFFu;
  for (int k = 0; k < K; ++k) {
    float bv = INFINITY; int bj = 0;
    #pragma unroll
    for (int j = 0; j < 16; ++j) {
      if (((mask >> j) & 1u) && d[j] < bv) { bv = d[j]; bj = j; }
    }
    int bp = bj*64 + lane;
    #pragma unroll
    for (int m = 1; m < 64; m <<= 1) {
      const float ov = __shfl_xor(bv, m);
      const int   op = __shfl_xor(bp, m);
      if (ov < bv || (ov == bv && op < bp)) { bv = ov; bp = op; }
    }
    if (lane == 0) knn_idx[(b*S+s)*K + k] = bp;
    if ((bp & 63) == lane) mask &= ~(1u << (bp >> 6));
  }
}

// ---------------- per-(b,s) mean over K + centered partial sums ----------------
__global__ void group_stats_kernel(const float* __restrict__ feats, const float* __restrict__ xyz,
                                   const int* __restrict__ knn_idx, float* __restrict__ mean_out,
                                   float2* __restrict__ partials) {
  const int bs = blockIdx.x;
  const int b = bs / S;
  const int t = threadIdx.x;              // 128
  __shared__ int sidx[K];
  if (t < K) sidx[t] = knn_idx[bs*K + t];
  __syncthreads();
  float v[K];
  float ls = 0.0f, lsq = 0.0f;
  if (t < GC) {
    float sum = 0.0f;
    #pragma unroll
    for (int k = 0; k < K; ++k) {
      const int p = sidx[k];
      const float g = (t < CF) ? feats[(b*N+p)*CF + t] : xyz[(b*N+p)*3 + (t-CF)];
      v[k] = g; sum += g;
    }
    const float mean = sum * (1.0f/K);
    mean_out[bs*GC + t] = mean;
    #pragma unroll
    for (int k = 0; k < K; ++k) {
      const float c = v[k] - mean;
      ls += c; lsq += c*c;
    }
  }
  __shared__ float r1[128], r2[128];
  r1[t] = ls; r2[t] = lsq;
  __syncthreads();
  for (int off = 64; off >= 1; off >>= 1) {
    if (t < off) { r1[t] += r1[t+off]; r2[t] += r2[t+off]; }
    __syncthreads();
  }
  if (t == 0) partials[bs] = make_float2(r1[0], r2[0]);
}

// ---------------- deterministic batch std (ddof=1), 64-lane double butterfly ----------------
__global__ void stats_kernel(const float2* __restrict__ partials, float* __restrict__ invstd) {
  const int b = blockIdx.x;
  const int lane = threadIdx.x;           // 64
  double su = 0.0, sq = 0.0;
  for (int i = lane; i < S; i += 64) {
    const float2 p = partials[b*S+i];
    su += (double)p.x; sq += (double)p.y;
  }
  #pragma unroll
  for (int m = 1; m < 64; m <<= 1) { su += __shfl_xor(su, m); sq += __shfl_xor(sq, m); }
  if (lane == 0) {
    const double nn = (double)S * K * GC;
    const double var = (sq - su*su/nn) / (nn - 1.0);
    invstd[b] = 1.0f / ((float)sqrt(var) + 1e-5f);
  }
}

// ---------------- transfer: normalize+affine, 1x1 conv + BN + ReLU + max over K
//                  + fused k/v projections of the produced row ----------------
__global__ void transfer_kernel(const float* __restrict__ feats, const float* __restrict__ xyz,
                                const int* __restrict__ knn_idx, const int* __restrict__ fps_idx,
                                const float* __restrict__ mean_in, const float* __restrict__ invstd,
                                const float* __restrict__ alpha, const float* __restrict__ beta,
                                const float* __restrict__ W_t, const float* __restrict__ b_t,
                                const float* __restrict__ bn_g, const float* __restrict__ bn_b,
                                const float* __restrict__ Wk, const float* __restrict__ bk,
                                const float* __restrict__ Wv, const float* __restrict__ bv,
                                float* __restrict__ v_k, float* __restrict__ kpb,
                                float* __restrict__ vpb) {
  const int bs = blockIdx.x;
  const int b = bs / S;
  const int t = threadIdx.x;              // 128
  __shared__ __align__(16) float np_s[K][DPAD];
  __shared__ float vrow[DM];
  __shared__ int sidx[K];
  __shared__ int sanchor;
  if (t < K) sidx[t] = knn_idx[bs*K + t];
  if (t == 0) sanchor = fps_idx[bs];
  __syncthreads();
  const float sinv = invstd[b];
  for (int k = 0; k < K; ++k) {
    const int p = sidx[k];
    for (int c = t; c < DPAD; c += 128) {
      float val = 0.0f;
      if (c < GC) {
        const float g = (c < CF) ? feats[(b*N+p)*CF + c] : xyz[(b*N+p)*3 + (c-CF)];
        val = (g - mean_in[bs*GC + c]) * sinv * alpha[c] + beta[c];
      } else if (c < DIN) {
        val = feats[(b*N+sanchor)*CF + (c - GC)];  // anchor feats, not normalized
      }
      np_s[k][c] = val;
    }
  }
  __syncthreads();
  float acc[K];
  const float bt = b_t[t];
  #pragma unroll
  for (int k = 0; k < K; ++k) acc[k] = bt;
  for (int d4 = 0; d4 < DPAD/4; ++d4) {
    const int d = d4*4;
    const float w0 = W_t[(d+0)*DM + t];
    const float w1 = W_t[(d+1)*DM + t];
    const float w2 = W_t[(d+2)*DM + t];
    const float w3 = (d+3 < DIN) ? W_t[(d+3)*DM + t] : 0.0f;
    #pragma unroll
    for (int k = 0; k < K; ++k) {
      const float4 f = *reinterpret_cast<const float4*>(&np_s[k][d]);
      acc[k] = acc[k] + f.x*w0 + f.y*w1 + f.z*w2 + f.w*w3;
    }
  }
  const float scale = bn_g[t] / sqrtf(1.0f + 1e-5f);
  const float shift = bn_b[t];
  float mx = -INFINITY;
  #pragma unroll
  for (int k = 0; k < K; ++k) {
    const float y = fmaxf(acc[k]*scale + shift, 0.0f);
    mx = fmaxf(mx, y);
  }
  v_k[bs*DM + t] = mx;
  vrow[t] = mx;
  __syncthreads();
  // fused k/v projections: same per-channel serial-d accumulation order as before
  float acck = bk[t], accv = bv[t];
  for (int d = 0; d < DM; ++d) {
    const float f = vrow[d];
    acck += f * Wk[d*DM + t];
    accv += f * Wv[d*DM + t];
  }
  kpb[bs*DM + t] = acck;
  vpb[bs*DM + t] = accv;
}

// ---------------- 3-NN inverse-distance interpolation + fused q projection ----------------
__global__ void interp_kernel(const float* __restrict__ xyz, const float* __restrict__ new_xyz,
                              const float* __restrict__ v_k, const float* __restrict__ Wq,
                              const float* __restrict__ bq, float* __restrict__ qbuf) {
  const int b = blockIdx.y;
  const int tid = threadIdx.x;            // 256
  const int wave = tid >> 6, lane = tid & 63;
  const int n = blockIdx.x*4 + wave;
  __shared__ float pts[S*3];
  __shared__ float vqs[4][DM];
  for (int i = tid; i < S*3; i += 256) pts[i] = new_xyz[b*S*3 + i];
  __syncthreads();
  const float qx = xyz[(b*N+n)*3+0], qy = xyz[(b*N+n)*3+1], qz = xyz[(b*N+n)*3+2];
  const float qn = qx*qx + qy*qy + qz*qz;
  float d[8];
  #pragma unroll
  for (int j = 0; j < 8; ++j) {
    const int p = j*64 + lane;
    const float px = pts[p*3+0], py = pts[p*3+1], pz = pts[p*3+2];
    const float dot = qx*px + qy*py + qz*pz;
    const float pn  = px*px + py*py + pz*pz;
    d[j] = (-2.0f*dot + qn) + pn;
  }
  unsigned mask = 0xFFu;
  float sd[3]; int sp[3];
  #pragma unroll
  for (int k = 0; k < 3; ++k) {
    float bv = INFINITY; int bj = 0;
    #pragma unroll
    for (int j = 0; j < 8; ++j) {
      if (((mask >> j) & 1u) && d[j] < bv) { bv = d[j]; bj = j; }
    }
    int bp = bj*64 + lane;
    #pragma unroll
    for (int m = 1; m < 64; m <<= 1) {
      const float ov = __shfl_xor(bv, m);
      const int   op = __shfl_xor(bp, m);
      if (ov < bv || (ov == bv && op < bp)) { bv = ov; bp = op; }
    }
    sd[k] = bv; sp[k] = bp;
    if ((bp & 63) == lane) mask &= ~(1u << (bp >> 6));
  }
  float w0 = 1.0f / fmaxf(sd[0], 1e-10f);
  float w1 = 1.0f / fmaxf(sd[1], 1e-10f);
  float w2 = 1.0f / fmaxf(sd[2], 1e-10f);
  const float wsum = w0 + w1 + w2;
  w0 /= wsum; w1 /= wsum; w2 /= wsum;
  const float* vk0 = v_k + (b*S + sp[0])*DM;
  const float* vk1 = v_k + (b*S + sp[1])*DM;
  const float* vk2 = v_k + (b*S + sp[2])*DM;
  #pragma unroll
  for (int c = lane; c < DM; c += 64) {
    vqs[wave][c] = w0*vk0[c] + w1*vk1[c] + w2*vk2[c];
  }
  __syncthreads();
  // fused q projection: each lane owns channels lane and lane+64 of its wave's row
  const float* row = vqs[wave];
  #pragma unroll
  for (int half = 0; half < 2; ++half) {
    const int c = lane + half*64;
    float acc = bq[c];
    for (int d = 0; d < DM; ++d) acc += row[d] * Wq[d*DM + c];
    qbuf[(b*N+n)*DM + c] = acc;
  }
}

// ---------------- cross-attention (RPE MLP fused, r10 inner) + output projection ----------------
__global__ void attn_kernel(const float* __restrict__ xyz, const float* __restrict__ new_xyz,
                            const float* __restrict__ qb, const float* __restrict__ kp,
                            const float* __restrict__ vp, const float* __restrict__ Wp1,
                            const float* __restrict__ bp1, const float* __restrict__ Wp2,
                            const float* __restrict__ bp2, const float* __restrict__ Wo,
                            const float* __restrict__ bo, float* __restrict__ out) {
  const int bn = blockIdx.x;              // b*N + n
  const int b = bn / N;
  const int t = threadIdx.x;              // 128
  __shared__ __align__(16) float e[NH][EPAD];
  __shared__ float qn_s[DM];
  __shared__ float oa[DM];
  __shared__ float ssum[NH];
  qn_s[t] = qb[bn*DM + t];
  __syncthreads();
  const float qx = xyz[bn*3+0], qy = xyz[bn*3+1], qz = xyz[bn*3+2];
  const float rs = 0.17677669529663687f;  // 1/sqrt(32)
  for (int j = t; j < S; j += 128) {
    const float px = new_xyz[(b*S+j)*3+0], py = new_xyz[(b*S+j)*3+1], pz = new_xyz[(b*S+j)*3+2];
    const float rx = qx-px, ry = qy-py, rz = qz-pz;
    float r0 = bp2[0], r1 = bp2[1], r2 = bp2[2], r3 = bp2[3];
    for (int m = 0; m < DM; ++m) {
      float hm = rx*Wp1[m] + ry*Wp1[DM+m] + rz*Wp1[2*DM+m] + bp1[m];
      hm = fmaxf(hm, 0.0f);
      r0 += hm*Wp2[m*NH+0]; r1 += hm*Wp2[m*NH+1];
      r2 += hm*Wp2[m*NH+2]; r3 += hm*Wp2[m*NH+3];
    }
    const float rpe[NH] = {r0, r1, r2, r3};
    #pragma unroll
    for (int h = 0; h < NH; ++h) {
      const float* kr = kp + (b*S+j)*DM + h*DH;
      const float* qr = qn_s + h*DH;
      float acc = 0.0f;
      #pragma unroll
      for (int dd = 0; dd < DH; ++dd) acc += qr[dd]*kr[dd];
      e[h][j] = acc*rs + rpe[h];
    }
  }
  __syncthreads();
  const int h = t >> 5, g = t & 31;       // 32 threads per head
  float mx = -INFINITY;
  for (int j = g; j < S; j += 32) mx = fmaxf(mx, e[h][j]);
  #pragma unroll
  for (int m = 16; m >= 1; m >>= 1) mx = fmaxf(mx, __shfl_xor(mx, m));
  float sum = 0.0f;
  for (int j = g; j < S; j += 32) { const float ex = expf(e[h][j]-mx); e[h][j] = ex; sum += ex; }
  #pragma unroll
  for (int m = 16; m >= 1; m >>= 1) sum += __shfl_xor(sum, m);
  if (g == 0) ssum[h] = sum;
  __syncthreads();
  float acc = 0.0f;
  for (int j = 0; j < S; j += 4) {
    const float4 ev = *reinterpret_cast<const float4*>(&e[h][j]);
    acc += ev.x * vp[(b*S+j+0)*DM + t];
    acc += ev.y * vp[(b*S+j+1)*DM + t];
    acc += ev.z * vp[(b*S+j+2)*DM + t];
    acc += ev.w * vp[(b*S+j+3)*DM + t];
  }
  oa[t] = acc / ssum[h];
  __syncthreads();
  float facc = bo[t];
  for (int d = 0; d < DM; ++d) facc += oa[d] * Wo[d*DM + t];
  out[bn*DM + t] = facc;
}

}  // namespace

extern "C" void kernel_launch(void* const* d_in, const int* in_sizes, int n_in,
                              void* d_out, int out_size, void* d_ws, size_t ws_size,
                              hipStream_t stream) {
  const float* xyz   = (const float*)d_in[0];
  const float* feats = (const float*)d_in[1];
  const float* alpha = (const float*)d_in[2];
  const float* beta  = (const float*)d_in[3];
  const float* W_t   = (const float*)d_in[4];
  const float* b_t   = (const float*)d_in[5];
  const float* bn_g  = (const float*)d_in[6];
  const float* bn_b  = (const float*)d_in[7];
  const float* Wq = (const float*)d_in[8];  const float* bq = (const float*)d_in[9];
  const float* Wk = (const float*)d_in[10]; const float* bk = (const float*)d_in[11];
  const float* Wv = (const float*)d_in[12]; const float* bv = (const float*)d_in[13];
  const float* Wo = (const float*)d_in[14]; const float* bo = (const float*)d_in[15];
  const float* Wp1= (const float*)d_in[16]; const float* bp1= (const float*)d_in[17];
  const float* Wp2= (const float*)d_in[18]; const float* bp2= (const float*)d_in[19];

  char* w = (char*)d_ws;
  int*    fps_i = (int*)   (w + 0);        // B*S ints            (4 KB)
  float*  nxyz  = (float*) (w + 4096);     // B*S*3               (12 KB)
  int*    knn_i = (int*)   (w + 16384);    // B*S*K ints          (128 KB)
  float*  meanb = (float*) (w + 147456);   // B*S*GC              (268 KB)
  float2* part  = (float2*)(w + 421888);   // B*S float2          (8 KB)
  float*  invs  = (float*) (w + 430080);   // B floats
  float*  vk    = (float*) (w + 430336);   // B*S*DM              (512 KB)
  float*  qbuf  = (float*) (w + 2003200);  // B*N*DM              (1 MB)
  float*  kpb   = (float*) (w + 3051776);  // B*S*DM              (512 KB)
  float*  vpb   = (float*) (w + 3576064);  // B*S*DM              (512 KB)
  float*  outf  = (float*)d_out;

  fps_kernel<<<FPS_GRID, 64, 0, stream>>>(xyz, fps_i, nxyz);
  knn_kernel<<<dim3(S/4, B), 256, 0, stream>>>(xyz, nxyz, knn_i);
  group_stats_kernel<<<B*S, 128, 0, stream>>>(feats, xyz, knn_i, meanb, part);
  stats_kernel<<<B, 64, 0, stream>>>(part, invs);
  transfer_kernel<<<B*S, 128, 0, stream>>>(feats, xyz, knn_i, fps_i, meanb, invs,
                                           alpha, beta, W_t, b_t, bn_g, bn_b,
                                           Wk, bk, Wv, bv, vk, kpb, vpb);
  interp_kernel<<<dim3(N/4, B), 256, 0, stream>>>(xyz, nxyz, vk, Wq, bq, qbuf);
  attn_kernel<<<B*N, 128, 0, stream>>>(xyz, nxyz, qbuf, kpb, vpb, Wp1, bp1, Wp2, bp2, Wo, bo, outf);
}

// Round 14
// 477.546 us; speedup vs baseline: 1.0146x; 1.0146x over previous
//
#include <hip/hip_runtime.h>
#include <math.h>

namespace {

constexpr int B  = 2;
constexpr int N  = 1024;
constexpr int CF = 64;    // C_FEAT
constexpr int S  = 512;
constexpr int K  = 32;
constexpr int DM = 128;   // D_MODEL
constexpr int NH = 4;
constexpr int DH = 32;
constexpr int GC = 67;    // grouped channels = CF + 3
constexpr int DIN = 131;  // GC + CF
constexpr int DPAD = 132; // padded row for float4 LDS reads
constexpr int EPAD = 516; // S+4: keeps e rows 16B-aligned for float4 reads

typedef float f2 __attribute__((ext_vector_type(2)));

__device__ inline float max3f(float a, float b, float c) { return fmaxf(fmaxf(a, b), c); }
__device__ inline unsigned min3u(unsigned a, unsigned b, unsigned c) { return min(min(a, b), c); }

// DPP helpers. Reduce-to-lane63 pattern: row_shr:1/2/4/8, row_bcast:15, row_bcast:31.
// bound_ctrl=true: invalid lanes read 0 — valid identity for u64-max of keys
// (dist>=0 -> hi>=0; lo=~idx>0 -> key>0).
template <int CTRL>
__device__ inline void dpp_max64(unsigned &hi, unsigned &lo) {
  const unsigned ohi = (unsigned)__builtin_amdgcn_update_dpp(0, (int)hi, CTRL, 0xF, 0xF, true);
  const unsigned olo = (unsigned)__builtin_amdgcn_update_dpp(0, (int)lo, CTRL, 0xF, 0xF, true);
  const bool gt = (ohi > hi) || ((ohi == hi) && (olo > lo));
  hi = gt ? ohi : hi;
  lo = gt ? olo : lo;
}

// ---------------- FPS: single wave per batch; pk-f32 update; SINGLE-PASS u64 DPP argmax ----------------
// Each lane owns 16 points; f2 slot j packs points (2j)*64+lane and (2j+1)*64+lane.
// Lane-local: max via max3 tree, then min index among local maxima (cnd/min3).
// Global: one 6-stage DPP u64-max on key (dist_bits<<32)|~idx -> (max dist,
// min index) = jnp.argmax first-occurrence semantics. One readlane per step
// (vs two DPP chains + two readlanes in the r10 two-pass form).
__global__ void __launch_bounds__(64, 1)
fps_kernel(const float* __restrict__ xyz, int* __restrict__ fps_idx,
           float* __restrict__ new_xyz) {
  const int b = blockIdx.x;
  const int lane = threadIdx.x;           // 64 threads = 1 wave
  __shared__ __align__(16) float4 pts4[N];
  __shared__ int farhist[S];
  for (int p = lane; p < N; p += 64) {
    pts4[p] = make_float4(xyz[b*N*3 + p*3+0], xyz[b*N*3 + p*3+1], xyz[b*N*3 + p*3+2], 0.0f);
  }
  __syncthreads();
  f2 X[8], Y[8], Z[8];
  float dist[16];
  #pragma unroll
  for (int j = 0; j < 8; ++j) {
    const float4 a = pts4[(2*j)*64 + lane];
    const float4 c = pts4[(2*j+1)*64 + lane];
    X[j] = f2{a.x, c.x}; Y[j] = f2{a.y, c.y}; Z[j] = f2{a.z, c.z};
  }
  #pragma unroll
  for (int k = 0; k < 16; ++k) dist[k] = 1e10f;
  int far = 0;
  for (int s = 0; s < S; ++s) {
    if (lane == 0) farhist[s] = far;
    const float4 c = pts4[far];
    const f2 cx = f2{c.x, c.x}, cy = f2{c.y, c.y}, cz = f2{c.z, c.z};
    #pragma unroll
    for (int j = 0; j < 8; ++j) {
      const f2 dx = X[j] - cx, dy = Y[j] - cy, dz = Z[j] - cz;
      const f2 q = dx*dx + dy*dy + dz*dz;    // same per-element expression as reference
      dist[2*j]   = fminf(dist[2*j],   q.x);
      dist[2*j+1] = fminf(dist[2*j+1], q.y);
    }
    // lane-local max via max3 tree (7 ops, depth 3)
    const float l0 = max3f(dist[0],  dist[1],  dist[2]);
    const float l1 = max3f(dist[3],  dist[4],  dist[5]);
    const float l2 = max3f(dist[6],  dist[7],  dist[8]);
    const float l3 = max3f(dist[9],  dist[10], dist[11]);
    const float l4 = max3f(dist[12], dist[13], dist[14]);
    const float mv = fmaxf(max3f(l0, l1, l2), max3f(l3, l4, dist[15]));
    // lane-local min index among local maxima (exact equality vs lane-local max)
    unsigned cnd[16];
    #pragma unroll
    for (int k = 0; k < 16; ++k) {
      cnd[k] = (dist[k] == mv) ? (unsigned)(k*64 + lane) : 0xFFFFFFFFu;
    }
    const unsigned u0 = min3u(cnd[0],  cnd[1],  cnd[2]);
    const unsigned u1 = min3u(cnd[3],  cnd[4],  cnd[5]);
    const unsigned u2 = min3u(cnd[6],  cnd[7],  cnd[8]);
    const unsigned u3 = min3u(cnd[9],  cnd[10], cnd[11]);
    const unsigned u4 = min3u(cnd[12], cnd[13], cnd[14]);
    const unsigned locidx = min(min3u(u0, u1, u2), min3u(u3, u4, cnd[15]));
    // single 6-stage DPP u64 max on (dist_bits<<32)|~idx -> lane 63
    unsigned hi = __float_as_uint(mv);
    unsigned lo = ~locidx;
    dpp_max64<0x111>(hi, lo);
    dpp_max64<0x112>(hi, lo);
    dpp_max64<0x114>(hi, lo);
    dpp_max64<0x118>(hi, lo);
    dpp_max64<0x142>(hi, lo);
    dpp_max64<0x143>(hi, lo);
    far = (int)~(unsigned)__builtin_amdgcn_readlane((int)lo, 63);
  }
  __syncthreads();
  // epilogue: write fps_idx and new_xyz from history
  for (int s = lane; s < S; s += 64) {
    const int f = farhist[s];
    const float4 c = pts4[f];
    fps_idx[b*S+s] = f;
    new_xyz[(b*S+s)*3+0] = c.x;
    new_xyz[(b*S+s)*3+1] = c.y;
    new_xyz[(b*S+s)*3+2] = c.z;
  }
}

// ---------------- KNN (K=32 of N=1024) + fused per-query group stats ----------------
// One wave per query. After selection (unchanged numerics), the same wave
// computes the query's channel means (same per-channel k-order -> bit-identical)
// and centered partial sums (butterfly grouping; feeds double-precision stats).
__global__ void knn_kernel(const float* __restrict__ xyz, const float* __restrict__ feats,
                           const float* __restrict__ new_xyz, int* __restrict__ knn_idx,
                           float* __restrict__ mean_out, float2* __restrict__ partials) {
  const int b = blockIdx.y;
  const int tid = threadIdx.x;            // 256
  const int wave = tid >> 6, lane = tid & 63;
  const int s = blockIdx.x * 4 + wave;
  __shared__ float pts[N*3];
  __shared__ int sidx_s[4][K];
  for (int i = tid; i < N*3; i += 256) pts[i] = xyz[b*N*3 + i];
  __syncthreads();
  const float qx = new_xyz[(b*S+s)*3+0], qy = new_xyz[(b*S+s)*3+1], qz = new_xyz[(b*S+s)*3+2];
  const float qn = qx*qx + qy*qy + qz*qz;
  float d[16];
  #pragma unroll
  for (int j = 0; j < 16; ++j) {
    const int p = j*64 + lane;
    const float px = pts[p*3+0], py = pts[p*3+1], pz = pts[p*3+2];
    const float dot = qx*px + qy*py + qz*pz;
    const float pn  = px*px + py*py + pz*pz;
    d[j] = (-2.0f*dot + qn) + pn;          // reference's expanded form + add order
  }
  unsigned mask = 0xFFFFu;
  for (int k = 0; k < K; ++k) {
    float bv = INFINITY; int bj = 0;
    #pragma unroll
    for (int j = 0; j < 16; ++j) {
      if (((mask >> j) & 1u) && d[j] < bv) { bv = d[j]; bj = j; }
    }
    int bp = bj*64 + lane;
    #pragma unroll
    for (int m = 1; m < 64; m <<= 1) {
      const float ov = __shfl_xor(bv, m);
      const int   op = __shfl_xor(bp, m);
      if (ov < bv || (ov == bv && op < bp)) { bv = ov; bp = op; }
    }
    if (lane == 0) { knn_idx[(b*S+s)*K + k] = bp; sidx_s[wave][k] = bp; }
    if ((bp & 63) == lane) mask &= ~(1u << (bp >> 6));
  }
  // ---- fused group stats for this query (wave-private; no block barrier) ----
  const int bs = b*S + s;
  float ls = 0.0f, lsq = 0.0f;
  float v[K];
  // phase A: channel c = lane (0..63, all < GC)
  {
    const int c = lane;
    float sum = 0.0f;
    #pragma unroll
    for (int k = 0; k < K; ++k) {
      const int p = sidx_s[wave][k];
      const float g = feats[(b*N+p)*CF + c];
      v[k] = g; sum += g;
    }
    const float mean = sum * (1.0f/K);
    mean_out[bs*GC + c] = mean;
    #pragma unroll
    for (int k = 0; k < K; ++k) {
      const float cc = v[k] - mean;
      ls += cc; lsq += cc*cc;
    }
  }
  // phase B: channels 64..66 (xyz), lanes 0..2
  if (lane < 3) {
    const int c = CF + lane;
    float sum = 0.0f;
    #pragma unroll
    for (int k = 0; k < K; ++k) {
      const int p = sidx_s[wave][k];
      const float g = xyz[(b*N+p)*3 + lane];
      v[k] = g; sum += g;
    }
    const float mean = sum * (1.0f/K);
    mean_out[bs*GC + c] = mean;
    #pragma unroll
    for (int k = 0; k < K; ++k) {
      const float cc = v[k] - mean;
      ls += cc; lsq += cc*cc;
    }
  }
  #pragma unroll
  for (int m = 1; m < 64; m <<= 1) { ls += __shfl_xor(ls, m); lsq += __shfl_xor(lsq, m); }
  if (lane == 0) partials[bs] = make_float2(ls, lsq);
}

// ---------------- deterministic batch std (ddof=1), 64-lane double butterfly ----------------
__global__ void stats_kernel(const float2* __restrict__ partials, float* __restrict__ invstd) {
  const int b = blockIdx.x;
  const int lane = threadIdx.x;           // 64
  double su = 0.0, sq = 0.0;
  for (int i = lane; i < S; i += 64) {
    const float2 p = partials[b*S+i];
    su += (double)p.x; sq += (double)p.y;
  }
  #pragma unroll
  for (int m = 1; m < 64; m <<= 1) { su += __shfl_xor(su, m); sq += __shfl_xor(sq, m); }
  if (lane == 0) {
    const double nn = (double)S * K * GC;
    const double var = (sq - su*su/nn) / (nn - 1.0);
    invstd[b] = 1.0f / ((float)sqrt(var) + 1e-5f);
  }
}

// ---------------- transfer: normalize+affine, 1x1 conv + BN + ReLU + max over K
//                  + fused k/v projections of the produced row ----------------
__global__ void transfer_kernel(const float* __restrict__ feats, const float* __restrict__ xyz,
                                const int* __restrict__ knn_idx, const int* __restrict__ fps_idx,
                                const float* __restrict__ mean_in, const float* __restrict__ invstd,
                                const float* __restrict__ alpha, const float* __restrict__ beta,
                                const float* __restrict__ W_t, const float* __restrict__ b_t,
                                const float* __restrict__ bn_g, const float* __restrict__ bn_b,
                                const float* __restrict__ Wk, const float* __restrict__ bk,
                                const float* __restrict__ Wv, const float* __restrict__ bv,
                                float* __restrict__ v_k, float* __restrict__ kpb,
                                float* __restrict__ vpb) {
  const int bs = blockIdx.x;
  const int b = bs / S;
  const int t = threadIdx.x;              // 128
  __shared__ __align__(16) float np_s[K][DPAD];
  __shared__ float vrow[DM];
  __shared__ int sidx[K];
  __shared__ int sanchor;
  if (t < K) sidx[t] = knn_idx[bs*K + t];
  if (t == 0) sanchor = fps_idx[bs];
  __syncthreads();
  const float sinv = invstd[b];
  for (int k = 0; k < K; ++k) {
    const int p = sidx[k];
    for (int c = t; c < DPAD; c += 128) {
      float val = 0.0f;
      if (c < GC) {
        const float g = (c < CF) ? feats[(b*N+p)*CF + c] : xyz[(b*N+p)*3 + (c-CF)];
        val = (g - mean_in[bs*GC + c]) * sinv * alpha[c] + beta[c];
      } else if (c < DIN) {
        val = feats[(b*N+sanchor)*CF + (c - GC)];  // anchor feats, not normalized
      }
      np_s[k][c] = val;
    }
  }
  __syncthreads();
  float acc[K];
  const float bt = b_t[t];
  #pragma unroll
  for (int k = 0; k < K; ++k) acc[k] = bt;
  for (int d4 = 0; d4 < DPAD/4; ++d4) {
    const int d = d4*4;
    const float w0 = W_t[(d+0)*DM + t];
    const float w1 = W_t[(d+1)*DM + t];
    const float w2 = W_t[(d+2)*DM + t];
    const float w3 = (d+3 < DIN) ? W_t[(d+3)*DM + t] : 0.0f;
    #pragma unroll
    for (int k = 0; k < K; ++k) {
      const float4 f = *reinterpret_cast<const float4*>(&np_s[k][d]);
      acc[k] = acc[k] + f.x*w0 + f.y*w1 + f.z*w2 + f.w*w3;
    }
  }
  const float scale = bn_g[t] / sqrtf(1.0f + 1e-5f);
  const float shift = bn_b[t];
  float mx = -INFINITY;
  #pragma unroll
  for (int k = 0; k < K; ++k) {
    const float y = fmaxf(acc[k]*scale + shift, 0.0f);
    mx = fmaxf(mx, y);
  }
  v_k[bs*DM + t] = mx;
  vrow[t] = mx;
  __syncthreads();
  // fused k/v projections: same per-channel serial-d accumulation order as before
  float acck = bk[t], accv = bv[t];
  for (int d = 0; d < DM; ++d) {
    const float f = vrow[d];
    acck += f * Wk[d*DM + t];
    accv += f * Wv[d*DM + t];
  }
  kpb[bs*DM + t] = acck;
  vpb[bs*DM + t] = accv;
}

// ---------------- 3-NN inverse-distance interpolation + fused q projection ----------------
__global__ void interp_kernel(const float* __restrict__ xyz, const float* __restrict__ new_xyz,
                              const float* __restrict__ v_k, const float* __restrict__ Wq,
                              const float* __restrict__ bq, float* __restrict__ qbuf) {
  const int b = blockIdx.y;
  const int tid = threadIdx.x;            // 256
  const int wave = tid >> 6, lane = tid & 63;
  const int n = blockIdx.x*4 + wave;
  __shared__ float pts[S*3];
  __shared__ float vqs[4][DM];
  for (int i = tid; i < S*3; i += 256) pts[i] = new_xyz[b*S*3 + i];
  __syncthreads();
  const float qx = xyz[(b*N+n)*3+0], qy = xyz[(b*N+n)*3+1], qz = xyz[(b*N+n)*3+2];
  const float qn = qx*qx + qy*qy + qz*qz;
  float d[8];
  #pragma unroll
  for (int j = 0; j < 8; ++j) {
    const int p = j*64 + lane;
    const float px = pts[p*3+0], py = pts[p*3+1], pz = pts[p*3+2];
    const float dot = qx*px + qy*py + qz*pz;
    const float pn  = px*px + py*py + pz*pz;
    d[j] = (-2.0f*dot + qn) + pn;
  }
  unsigned mask = 0xFFu;
  float sd[3]; int sp[3];
  #pragma unroll
  for (int k = 0; k < 3; ++k) {
    float bv = INFINITY; int bj = 0;
    #pragma unroll
    for (int j = 0; j < 8; ++j) {
      if (((mask >> j) & 1u) && d[j] < bv) { bv = d[j]; bj = j; }
    }
    int bp = bj*64 + lane;
    #pragma unroll
    for (int m = 1; m < 64; m <<= 1) {
      const float ov = __shfl_xor(bv, m);
      const int   op = __shfl_xor(bp, m);
      if (ov < bv || (ov == bv && op < bp)) { bv = ov; bp = op; }
    }
    sd[k] = bv; sp[k] = bp;
    if ((bp & 63) == lane) mask &= ~(1u << (bp >> 6));
  }
  float w0 = 1.0f / fmaxf(sd[0], 1e-10f);
  float w1 = 1.0f / fmaxf(sd[1], 1e-10f);
  float w2 = 1.0f / fmaxf(sd[2], 1e-10f);
  const float wsum = w0 + w1 + w2;
  w0 /= wsum; w1 /= wsum; w2 /= wsum;
  const float* vk0 = v_k + (b*S + sp[0])*DM;
  const float* vk1 = v_k + (b*S + sp[1])*DM;
  const float* vk2 = v_k + (b*S + sp[2])*DM;
  #pragma unroll
  for (int c = lane; c < DM; c += 64) {
    vqs[wave][c] = w0*vk0[c] + w1*vk1[c] + w2*vk2[c];
  }
  __syncthreads();
  // fused q projection: each lane owns channels lane and lane+64 of its wave's row
  const float* row = vqs[wave];
  #pragma unroll
  for (int half = 0; half < 2; ++half) {
    const int c = lane + half*64;
    float acc = bq[c];
    for (int d = 0; d < DM; ++d) acc += row[d] * Wq[d*DM + c];
    qbuf[(b*N+n)*DM + c] = acc;
  }
}

// ---------------- cross-attention (RPE MLP fused, r10 inner) + output projection ----------------
__global__ void attn_kernel(const float* __restrict__ xyz, const float* __restrict__ new_xyz,
                            const float* __restrict__ qb, const float* __restrict__ kp,
                            const float* __restrict__ vp, const float* __restrict__ Wp1,
                            const float* __restrict__ bp1, const float* __restrict__ Wp2,
                            const float* __restrict__ bp2, const float* __restrict__ Wo,
                            const float* __restrict__ bo, float* __restrict__ out) {
  const int bn = blockIdx.x;              // b*N + n
  const int b = bn / N;
  const int t = threadIdx.x;              // 128
  __shared__ __align__(16) float e[NH][EPAD];
  __shared__ float qn_s[DM];
  __shared__ float oa[DM];
  __shared__ float ssum[NH];
  qn_s[t] = qb[bn*DM + t];
  __syncthreads();
  const float qx = xyz[bn*3+0], qy = xyz[bn*3+1], qz = xyz[bn*3+2];
  const float rs = 0.17677669529663687f;  // 1/sqrt(32)
  for (int j = t; j < S; j += 128) {
    const float px = new_xyz[(b*S+j)*3+0], py = new_xyz[(b*S+j)*3+1], pz = new_xyz[(b*S+j)*3+2];
    const float rx = qx-px, ry = qy-py, rz = qz-pz;
    float r0 = bp2[0], r1 = bp2[1], r2 = bp2[2], r3 = bp2[3];
    for (int m = 0; m < DM; ++m) {
      float hm = rx*Wp1[m] + ry*Wp1[DM+m] + rz*Wp1[2*DM+m] + bp1[m];
      hm = fmaxf(hm, 0.0f);
      r0 += hm*Wp2[m*NH+0]; r1 += hm*Wp2[m*NH+1];
      r2 += hm*Wp2[m*NH+2]; r3 += hm*Wp2[m*NH+3];
    }
    const float rpe[NH] = {r0, r1, r2, r3};
    #pragma unroll
    for (int h = 0; h < NH; ++h) {
      const float* kr = kp + (b*S+j)*DM + h*DH;
      const float* qr = qn_s + h*DH;
      float acc = 0.0f;
      #pragma unroll
      for (int dd = 0; dd < DH; ++dd) acc += qr[dd]*kr[dd];
      e[h][j] = acc*rs + rpe[h];
    }
  }
  __syncthreads();
  const int h = t >> 5, g = t & 31;       // 32 threads per head
  float mx = -INFINITY;
  for (int j = g; j < S; j += 32) mx = fmaxf(mx, e[h][j]);
  #pragma unroll
  for (int m = 16; m >= 1; m >>= 1) mx = fmaxf(mx, __shfl_xor(mx, m));
  float sum = 0.0f;
  for (int j = g; j < S; j += 32) { const float ex = expf(e[h][j]-mx); e[h][j] = ex; sum += ex; }
  #pragma unroll
  for (int m = 16; m >= 1; m >>= 1) sum += __shfl_xor(sum, m);
  if (g == 0) ssum[h] = sum;
  __syncthreads();
  float acc = 0.0f;
  for (int j = 0; j < S; j += 4) {
    const float4 ev = *reinterpret_cast<const float4*>(&e[h][j]);
    acc += ev.x * vp[(b*S+j+0)*DM + t];
    acc += ev.y * vp[(b*S+j+1)*DM + t];
    acc += ev.z * vp[(b*S+j+2)*DM + t];
    acc += ev.w * vp[(b*S+j+3)*DM + t];
  }
  oa[t] = acc / ssum[h];
  __syncthreads();
  float facc = bo[t];
  for (int d = 0; d < DM; ++d) facc += oa[d] * Wo[d*DM + t];
  out[bn*DM + t] = facc;
}

}  // namespace

extern "C" void kernel_launch(void* const* d_in, const int* in_sizes, int n_in,
                              void* d_out, int out_size, void* d_ws, size_t ws_size,
                              hipStream_t stream) {
  const float* xyz   = (const float*)d_in[0];
  const float* feats = (const float*)d_in[1];
  const float* alpha = (const float*)d_in[2];
  const float* beta  = (const float*)d_in[3];
  const float* W_t   = (const float*)d_in[4];
  const float* b_t   = (const float*)d_in[5];
  const float* bn_g  = (const float*)d_in[6];
  const float* bn_b  = (const float*)d_in[7];
  const float* Wq = (const float*)d_in[8];  const float* bq = (const float*)d_in[9];
  const float* Wk = (const float*)d_in[10]; const float* bk = (const float*)d_in[11];
  const float* Wv = (const float*)d_in[12]; const float* bv = (const float*)d_in[13];
  const float* Wo = (const float*)d_in[14]; const float* bo = (const float*)d_in[15];
  const float* Wp1= (const float*)d_in[16]; const float* bp1= (const float*)d_in[17];
  const float* Wp2= (const float*)d_in[18]; const float* bp2= (const float*)d_in[19];

  char* w = (char*)d_ws;
  int*    fps_i = (int*)   (w + 0);        // B*S ints            (4 KB)
  float*  nxyz  = (float*) (w + 4096);     // B*S*3               (12 KB)
  int*    knn_i = (int*)   (w + 16384);    // B*S*K ints          (128 KB)
  float*  meanb = (float*) (w + 147456);   // B*S*GC              (268 KB)
  float2* part  = (float2*)(w + 421888);   // B*S float2          (8 KB)
  float*  invs  = (float*) (w + 430080);   // B floats
  float*  vk    = (float*) (w + 430336);   // B*S*DM              (512 KB)
  float*  qbuf  = (float*) (w + 2003200);  // B*N*DM              (1 MB)
  float*  kpb   = (float*) (w + 3051776);  // B*S*DM              (512 KB)
  float*  vpb   = (float*) (w + 3576064);  // B*S*DM              (512 KB)
  float*  outf  = (float*)d_out;

  fps_kernel<<<B, 64, 0, stream>>>(xyz, fps_i, nxyz);
  knn_kernel<<<dim3(S/4, B), 256, 0, stream>>>(xyz, feats, nxyz, knn_i, meanb, part);
  stats_kernel<<<B, 64, 0, stream>>>(part, invs);
  transfer_kernel<<<B*S, 128, 0, stream>>>(feats, xyz, knn_i, fps_i, meanb, invs,
                                           alpha, beta, W_t, b_t, bn_g, bn_b,
                                           Wk, bk, Wv, bv, vk, kpb, vpb);
  interp_kernel<<<dim3(N/4, B), 256, 0, stream>>>(xyz, nxyz, vk, Wq, bq, qbuf);
  attn_kernel<<<B*N, 128, 0, stream>>>(xyz, nxyz, qbuf, kpb, vpb, Wp1, bp1, Wp2, bp2, Wo, bo, outf);
}

// Round 15
// 465.494 us; speedup vs baseline: 1.0409x; 1.0259x over previous
//
#include <hip/hip_runtime.h>
#include <math.h>

namespace {

constexpr int B  = 2;
constexpr int N  = 1024;
constexpr int CF = 64;    // C_FEAT
constexpr int S  = 512;
constexpr int K  = 32;
constexpr int DM = 128;   // D_MODEL
constexpr int NH = 4;
constexpr int DH = 32;
constexpr int GC = 67;    // grouped channels = CF + 3
constexpr int DIN = 131;  // GC + CF
constexpr int DPAD = 132; // padded row for float4 LDS reads
constexpr int EPAD = 516; // S+4: keeps e rows 16B-aligned for float4 reads

typedef float f2 __attribute__((ext_vector_type(2)));

__device__ inline float max3f(float a, float b, float c) { return fmaxf(fmaxf(a, b), c); }
__device__ inline unsigned min3u(unsigned a, unsigned b, unsigned c) { return min(min(a, b), c); }

// DPP helpers. Reduce-to-lane63 pattern: row_shr:1/2/4/8, row_bcast:15, row_bcast:31.
template <int CTRL>
__device__ inline float dpp_mov_f(float v) {
  // bound_ctrl=true: invalid lanes read 0 — valid identity for fmax of nonneg values.
  return __int_as_float(__builtin_amdgcn_update_dpp(0, __float_as_int(v), CTRL, 0xF, 0xF, true));
}
template <int CTRL>
__device__ inline unsigned dpp_mov_self_u(unsigned v) {
  // bound_ctrl=false with old=v: invalid lanes yield v — identity for min.
  return (unsigned)__builtin_amdgcn_update_dpp((int)v, (int)v, CTRL, 0xF, 0xF, false);
}

// ---------------- FPS (r10 exact): single wave per batch, pk-f32 update, two-pass DPP argmax ----------------
// Reduce-ledger winner (225us): two-pass f32 DPP (vs 250 u64 / 274 ballot / 298 bpermute).
__global__ void __launch_bounds__(64, 1)
fps_kernel(const float* __restrict__ xyz, int* __restrict__ fps_idx,
           float* __restrict__ new_xyz) {
  const int b = blockIdx.x;
  const int lane = threadIdx.x;           // 64 threads = 1 wave
  __shared__ __align__(16) float4 pts4[N];
  __shared__ int farhist[S];
  for (int p = lane; p < N; p += 64) {
    pts4[p] = make_float4(xyz[b*N*3 + p*3+0], xyz[b*N*3 + p*3+1], xyz[b*N*3 + p*3+2], 0.0f);
  }
  __syncthreads();
  f2 X[8], Y[8], Z[8];
  float dist[16];
  #pragma unroll
  for (int j = 0; j < 8; ++j) {
    const float4 a = pts4[(2*j)*64 + lane];
    const float4 c = pts4[(2*j+1)*64 + lane];
    X[j] = f2{a.x, c.x}; Y[j] = f2{a.y, c.y}; Z[j] = f2{a.z, c.z};
  }
  #pragma unroll
  for (int k = 0; k < 16; ++k) dist[k] = 1e10f;
  int far = 0;
  for (int s = 0; s < S; ++s) {
    if (lane == 0) farhist[s] = far;
    const float4 c = pts4[far];
    const f2 cx = f2{c.x, c.x}, cy = f2{c.y, c.y}, cz = f2{c.z, c.z};
    #pragma unroll
    for (int j = 0; j < 8; ++j) {
      const f2 dx = X[j] - cx, dy = Y[j] - cy, dz = Z[j] - cz;
      const f2 q = dx*dx + dy*dy + dz*dz;    // same per-element expression as reference
      dist[2*j]   = fminf(dist[2*j],   q.x);
      dist[2*j+1] = fminf(dist[2*j+1], q.y);
    }
    // pass 1: lane-local max via max3 tree (7 ops, depth 3)
    const float l0 = max3f(dist[0],  dist[1],  dist[2]);
    const float l1 = max3f(dist[3],  dist[4],  dist[5]);
    const float l2 = max3f(dist[6],  dist[7],  dist[8]);
    const float l3 = max3f(dist[9],  dist[10], dist[11]);
    const float l4 = max3f(dist[12], dist[13], dist[14]);
    float mv = fmaxf(max3f(l0, l1, l2), max3f(l3, l4, dist[15]));
    // wave64 max via DPP, result valid in lane 63
    mv = fmaxf(mv, dpp_mov_f<0x111>(mv));
    mv = fmaxf(mv, dpp_mov_f<0x112>(mv));
    mv = fmaxf(mv, dpp_mov_f<0x114>(mv));
    mv = fmaxf(mv, dpp_mov_f<0x118>(mv));
    mv = fmaxf(mv, dpp_mov_f<0x142>(mv));
    mv = fmaxf(mv, dpp_mov_f<0x143>(mv));
    const float maxv = __int_as_float(__builtin_amdgcn_readlane(__float_as_int(mv), 63));
    // pass 2: min index among exact maxima (min3 tree)
    unsigned cnd[16];
    #pragma unroll
    for (int k = 0; k < 16; ++k) {
      cnd[k] = (dist[k] == maxv) ? (unsigned)(k*64 + lane) : 0xFFFFFFFFu;
    }
    const unsigned u0 = min3u(cnd[0],  cnd[1],  cnd[2]);
    const unsigned u1 = min3u(cnd[3],  cnd[4],  cnd[5]);
    const unsigned u2 = min3u(cnd[6],  cnd[7],  cnd[8]);
    const unsigned u3 = min3u(cnd[9],  cnd[10], cnd[11]);
    const unsigned u4 = min3u(cnd[12], cnd[13], cnd[14]);
    unsigned cand = min(min3u(u0, u1, u2), min3u(u3, u4, cnd[15]));
    cand = min(cand, dpp_mov_self_u<0x111>(cand));
    cand = min(cand, dpp_mov_self_u<0x112>(cand));
    cand = min(cand, dpp_mov_self_u<0x114>(cand));
    cand = min(cand, dpp_mov_self_u<0x118>(cand));
    cand = min(cand, dpp_mov_self_u<0x142>(cand));
    cand = min(cand, dpp_mov_self_u<0x143>(cand));
    far = __builtin_amdgcn_readlane((int)cand, 63);
  }
  __syncthreads();
  // epilogue: write fps_idx and new_xyz from history
  for (int s = lane; s < S; s += 64) {
    const int f = farhist[s];
    const float4 c = pts4[f];
    fps_idx[b*S+s] = f;
    new_xyz[(b*S+s)*3+0] = c.x;
    new_xyz[(b*S+s)*3+1] = c.y;
    new_xyz[(b*S+s)*3+2] = c.z;
  }
}

// ---------------- KNN (K=32 of N=1024) + fused per-query group stats (r14, neutral-keep) ----------------
__global__ void knn_kernel(const float* __restrict__ xyz, const float* __restrict__ feats,
                           const float* __restrict__ new_xyz, int* __restrict__ knn_idx,
                           float* __restrict__ mean_out, float2* __restrict__ partials) {
  const int b = blockIdx.y;
  const int tid = threadIdx.x;            // 256
  const int wave = tid >> 6, lane = tid & 63;
  const int s = blockIdx.x * 4 + wave;
  __shared__ float pts[N*3];
  __shared__ int sidx_s[4][K];
  for (int i = tid; i < N*3; i += 256) pts[i] = xyz[b*N*3 + i];
  __syncthreads();
  const float qx = new_xyz[(b*S+s)*3+0], qy = new_xyz[(b*S+s)*3+1], qz = new_xyz[(b*S+s)*3+2];
  const float qn = qx*qx + qy*qy + qz*qz;
  float d[16];
  #pragma unroll
  for (int j = 0; j < 16; ++j) {
    const int p = j*64 + lane;
    const float px = pts[p*3+0], py = pts[p*3+1], pz = pts[p*3+2];
    const float dot = qx*px + qy*py + qz*pz;
    const float pn  = px*px + py*py + pz*pz;
    d[j] = (-2.0f*dot + qn) + pn;          // reference's expanded form + add order
  }
  unsigned mask = 0xFFFFu;
  for (int k = 0; k < K; ++k) {
    float bv = INFINITY; int bj = 0;
    #pragma unroll
    for (int j = 0; j < 16; ++j) {
      if (((mask >> j) & 1u) && d[j] < bv) { bv = d[j]; bj = j; }
    }
    int bp = bj*64 + lane;
    #pragma unroll
    for (int m = 1; m < 64; m <<= 1) {
      const float ov = __shfl_xor(bv, m);
      const int   op = __shfl_xor(bp, m);
      if (ov < bv || (ov == bv && op < bp)) { bv = ov; bp = op; }
    }
    if (lane == 0) { knn_idx[(b*S+s)*K + k] = bp; sidx_s[wave][k] = bp; }
    if ((bp & 63) == lane) mask &= ~(1u << (bp >> 6));
  }
  // fused group stats for this query (wave-private; no block barrier)
  const int bs = b*S + s;
  float ls = 0.0f, lsq = 0.0f;
  float v[K];
  {
    const int c = lane;                    // channels 0..63 (< GC)
    float sum = 0.0f;
    #pragma unroll
    for (int k = 0; k < K; ++k) {
      const int p = sidx_s[wave][k];
      const float g = feats[(b*N+p)*CF + c];
      v[k] = g; sum += g;
    }
    const float mean = sum * (1.0f/K);
    mean_out[bs*GC + c] = mean;
    #pragma unroll
    for (int k = 0; k < K; ++k) {
      const float cc = v[k] - mean;
      ls += cc; lsq += cc*cc;
    }
  }
  if (lane < 3) {                          // channels 64..66 (xyz)
    const int c = CF + lane;
    float sum = 0.0f;
    #pragma unroll
    for (int k = 0; k < K; ++k) {
      const int p = sidx_s[wave][k];
      const float g = xyz[(b*N+p)*3 + lane];
      v[k] = g; sum += g;
    }
    const float mean = sum * (1.0f/K);
    mean_out[bs*GC + c] = mean;
    #pragma unroll
    for (int k = 0; k < K; ++k) {
      const float cc = v[k] - mean;
      ls += cc; lsq += cc*cc;
    }
  }
  #pragma unroll
  for (int m = 1; m < 64; m <<= 1) { ls += __shfl_xor(ls, m); lsq += __shfl_xor(lsq, m); }
  if (lane == 0) partials[bs] = make_float2(ls, lsq);
}

// ---------------- deterministic batch std (ddof=1), 64-lane double butterfly ----------------
__global__ void stats_kernel(const float2* __restrict__ partials, float* __restrict__ invstd) {
  const int b = blockIdx.x;
  const int lane = threadIdx.x;           // 64
  double su = 0.0, sq = 0.0;
  for (int i = lane; i < S; i += 64) {
    const float2 p = partials[b*S+i];
    su += (double)p.x; sq += (double)p.y;
  }
  #pragma unroll
  for (int m = 1; m < 64; m <<= 1) { su += __shfl_xor(su, m); sq += __shfl_xor(sq, m); }
  if (lane == 0) {
    const double nn = (double)S * K * GC;
    const double var = (sq - su*su/nn) / (nn - 1.0);
    invstd[b] = 1.0f / ((float)sqrt(var) + 1e-5f);
  }
}

// ---------------- transfer: normalize+affine, 1x1 conv (pk-f32 acc) + BN + ReLU + max over K
//                  + fused k/v projections ----------------
__global__ void transfer_kernel(const float* __restrict__ feats, const float* __restrict__ xyz,
                                const int* __restrict__ knn_idx, const int* __restrict__ fps_idx,
                                const float* __restrict__ mean_in, const float* __restrict__ invstd,
                                const float* __restrict__ alpha, const float* __restrict__ beta,
                                const float* __restrict__ W_t, const float* __restrict__ b_t,
                                const float* __restrict__ bn_g, const float* __restrict__ bn_b,
                                const float* __restrict__ Wk, const float* __restrict__ bk,
                                const float* __restrict__ Wv, const float* __restrict__ bv,
                                float* __restrict__ v_k, float* __restrict__ kpb,
                                float* __restrict__ vpb) {
  const int bs = blockIdx.x;
  const int b = bs / S;
  const int t = threadIdx.x;              // 128
  __shared__ __align__(16) float np_s[K][DPAD];
  __shared__ float vrow[DM];
  __shared__ int sidx[K];
  __shared__ int sanchor;
  if (t < K) sidx[t] = knn_idx[bs*K + t];
  if (t == 0) sanchor = fps_idx[bs];
  __syncthreads();
  const float sinv = invstd[b];
  for (int k = 0; k < K; ++k) {
    const int p = sidx[k];
    for (int c = t; c < DPAD; c += 128) {
      float val = 0.0f;
      if (c < GC) {
        const float g = (c < CF) ? feats[(b*N+p)*CF + c] : xyz[(b*N+p)*3 + (c-CF)];
        val = (g - mean_in[bs*GC + c]) * sinv * alpha[c] + beta[c];
      } else if (c < DIN) {
        val = feats[(b*N+sanchor)*CF + (c - GC)];  // anchor feats, not normalized
      }
      np_s[k][c] = val;
    }
  }
  __syncthreads();
  // pk-f32 accumulate: acc2[k] = (bt + sum f.x*w0 + f.z*w2, sum f.y*w1 + f.w*w3);
  // final acc[k] = .x + .y (reassociation only; pre-BN/ReLU/max, well within tolerance).
  f2 acc2[K];
  const float bt = b_t[t];
  #pragma unroll
  for (int k = 0; k < K; ++k) acc2[k] = f2{bt, 0.0f};
  for (int d4 = 0; d4 < DPAD/4; ++d4) {
    const int d = d4*4;
    const float w0 = W_t[(d+0)*DM + t];
    const float w1 = W_t[(d+1)*DM + t];
    const float w2 = W_t[(d+2)*DM + t];
    const float w3 = (d+3 < DIN) ? W_t[(d+3)*DM + t] : 0.0f;
    const f2 w01 = f2{w0, w1};
    const f2 w23 = f2{w2, w3};
    #pragma unroll
    for (int k = 0; k < K; ++k) {
      const float4 f = *reinterpret_cast<const float4*>(&np_s[k][d]);
      acc2[k] += f2{f.x, f.y} * w01 + f2{f.z, f.w} * w23;
    }
  }
  const float scale = bn_g[t] / sqrtf(1.0f + 1e-5f);
  const float shift = bn_b[t];
  float mx = -INFINITY;
  #pragma unroll
  for (int k = 0; k < K; ++k) {
    const float a = acc2[k].x + acc2[k].y;
    const float y = fmaxf(a*scale + shift, 0.0f);
    mx = fmaxf(mx, y);
  }
  v_k[bs*DM + t] = mx;
  vrow[t] = mx;
  __syncthreads();
  // fused k/v projections: same per-channel serial-d accumulation order as before
  float acck = bk[t], accv = bv[t];
  for (int d = 0; d < DM; ++d) {
    const float f = vrow[d];
    acck += f * Wk[d*DM + t];
    accv += f * Wv[d*DM + t];
  }
  kpb[bs*DM + t] = acck;
  vpb[bs*DM + t] = accv;
}

// ---------------- 3-NN inverse-distance interpolation + fused q projection ----------------
__global__ void interp_kernel(const float* __restrict__ xyz, const float* __restrict__ new_xyz,
                              const float* __restrict__ v_k, const float* __restrict__ Wq,
                              const float* __restrict__ bq, float* __restrict__ qbuf) {
  const int b = blockIdx.y;
  const int tid = threadIdx.x;            // 256
  const int wave = tid >> 6, lane = tid & 63;
  const int n = blockIdx.x*4 + wave;
  __shared__ float pts[S*3];
  __shared__ float vqs[4][DM];
  for (int i = tid; i < S*3; i += 256) pts[i] = new_xyz[b*S*3 + i];
  __syncthreads();
  const float qx = xyz[(b*N+n)*3+0], qy = xyz[(b*N+n)*3+1], qz = xyz[(b*N+n)*3+2];
  const float qn = qx*qx + qy*qy + qz*qz;
  float d[8];
  #pragma unroll
  for (int j = 0; j < 8; ++j) {
    const int p = j*64 + lane;
    const float px = pts[p*3+0], py = pts[p*3+1], pz = pts[p*3+2];
    const float dot = qx*px + qy*py + qz*pz;
    const float pn  = px*px + py*py + pz*pz;
    d[j] = (-2.0f*dot + qn) + pn;
  }
  unsigned mask = 0xFFu;
  float sd[3]; int sp[3];
  #pragma unroll
  for (int k = 0; k < 3; ++k) {
    float bv = INFINITY; int bj = 0;
    #pragma unroll
    for (int j = 0; j < 8; ++j) {
      if (((mask >> j) & 1u) && d[j] < bv) { bv = d[j]; bj = j; }
    }
    int bp = bj*64 + lane;
    #pragma unroll
    for (int m = 1; m < 64; m <<= 1) {
      const float ov = __shfl_xor(bv, m);
      const int   op = __shfl_xor(bp, m);
      if (ov < bv || (ov == bv && op < bp)) { bv = ov; bp = op; }
    }
    sd[k] = bv; sp[k] = bp;
    if ((bp & 63) == lane) mask &= ~(1u << (bp >> 6));
  }
  float w0 = 1.0f / fmaxf(sd[0], 1e-10f);
  float w1 = 1.0f / fmaxf(sd[1], 1e-10f);
  float w2 = 1.0f / fmaxf(sd[2], 1e-10f);
  const float wsum = w0 + w1 + w2;
  w0 /= wsum; w1 /= wsum; w2 /= wsum;
  const float* vk0 = v_k + (b*S + sp[0])*DM;
  const float* vk1 = v_k + (b*S + sp[1])*DM;
  const float* vk2 = v_k + (b*S + sp[2])*DM;
  #pragma unroll
  for (int c = lane; c < DM; c += 64) {
    vqs[wave][c] = w0*vk0[c] + w1*vk1[c] + w2*vk2[c];
  }
  __syncthreads();
  // fused q projection: each lane owns channels lane and lane+64 of its wave's row
  const float* row = vqs[wave];
  #pragma unroll
  for (int half = 0; half < 2; ++half) {
    const int c = lane + half*64;
    float acc = bq[c];
    for (int d = 0; d < DM; ++d) acc += row[d] * Wq[d*DM + c];
    qbuf[(b*N+n)*DM + c] = acc;
  }
}

// ---------------- cross-attention (RPE pk-f32 over j-pairs) + output projection ----------------
__global__ void attn_kernel(const float* __restrict__ xyz, const float* __restrict__ new_xyz,
                            const float* __restrict__ qb, const float* __restrict__ kp,
                            const float* __restrict__ vp, const float* __restrict__ Wp1,
                            const float* __restrict__ bp1, const float* __restrict__ Wp2,
                            const float* __restrict__ bp2, const float* __restrict__ Wo,
                            const float* __restrict__ bo, float* __restrict__ out) {
  const int bn = blockIdx.x;              // b*N + n
  const int b = bn / N;
  const int t = threadIdx.x;              // 128
  __shared__ __align__(16) float e[NH][EPAD];
  __shared__ float qn_s[DM];
  __shared__ float oa[DM];
  __shared__ float ssum[NH];
  qn_s[t] = qb[bn*DM + t];
  __syncthreads();
  const float qx = xyz[bn*3+0], qy = xyz[bn*3+1], qz = xyz[bn*3+2];
  const float rs = 0.17677669529663687f;  // 1/sqrt(32)
  // RPE over 4 j's (j = t + jj*128) packed into 2 f2 pairs -> v_pk_fma.
  // Each j's accumulation chain over m is element-independent and unchanged.
  {
    f2 rx2[2], ry2[2], rz2[2];
    f2 r0p[2], r1p[2], r2p[2], r3p[2];
    #pragma unroll
    for (int p = 0; p < 2; ++p) {
      const int j0 = t + (2*p)*128, j1 = t + (2*p+1)*128;
      const float px0 = new_xyz[(b*S+j0)*3+0], py0 = new_xyz[(b*S+j0)*3+1], pz0 = new_xyz[(b*S+j0)*3+2];
      const float px1 = new_xyz[(b*S+j1)*3+0], py1 = new_xyz[(b*S+j1)*3+1], pz1 = new_xyz[(b*S+j1)*3+2];
      rx2[p] = f2{qx-px0, qx-px1};
      ry2[p] = f2{qy-py0, qy-py1};
      rz2[p] = f2{qz-pz0, qz-pz1};
      r0p[p] = f2{bp2[0], bp2[0]}; r1p[p] = f2{bp2[1], bp2[1]};
      r2p[p] = f2{bp2[2], bp2[2]}; r3p[p] = f2{bp2[3], bp2[3]};
    }
    for (int m = 0; m < DM; ++m) {
      const float w1 = Wp1[m], w2 = Wp1[DM+m], w3 = Wp1[2*DM+m], bb = bp1[m];
      const float p0 = Wp2[m*NH+0], p1 = Wp2[m*NH+1], p2 = Wp2[m*NH+2], p3 = Wp2[m*NH+3];
      #pragma unroll
      for (int p = 0; p < 2; ++p) {
        f2 hm = rx2[p]*w1 + ry2[p]*w2 + rz2[p]*w3 + bb;
        hm.x = fmaxf(hm.x, 0.0f);
        hm.y = fmaxf(hm.y, 0.0f);
        r0p[p] += hm*p0; r1p[p] += hm*p1; r2p[p] += hm*p2; r3p[p] += hm*p3;
      }
    }
    #pragma unroll
    for (int jj = 0; jj < 4; ++jj) {
      const int j = t + jj*128;
      const int p = jj >> 1;
      const float rpe[NH] = {
        (jj & 1) ? r0p[p].y : r0p[p].x,
        (jj & 1) ? r1p[p].y : r1p[p].x,
        (jj & 1) ? r2p[p].y : r2p[p].x,
        (jj & 1) ? r3p[p].y : r3p[p].x };
      #pragma unroll
      for (int h = 0; h < NH; ++h) {
        const float* kr = kp + (b*S+j)*DM + h*DH;
        const float* qr = qn_s + h*DH;
        float acc = 0.0f;
        #pragma unroll
        for (int dd = 0; dd < DH; ++dd) acc += qr[dd]*kr[dd];
        e[h][j] = acc*rs + rpe[h];
      }
    }
  }
  __syncthreads();
  const int h = t >> 5, g = t & 31;       // 32 threads per head
  float mx = -INFINITY;
  for (int j = g; j < S; j += 32) mx = fmaxf(mx, e[h][j]);
  #pragma unroll
  for (int m = 16; m >= 1; m >>= 1) mx = fmaxf(mx, __shfl_xor(mx, m));
  float sum = 0.0f;
  for (int j = g; j < S; j += 32) { const float ex = expf(e[h][j]-mx); e[h][j] = ex; sum += ex; }
  #pragma unroll
  for (int m = 16; m >= 1; m >>= 1) sum += __shfl_xor(sum, m);
  if (g == 0) ssum[h] = sum;
  __syncthreads();
  float acc = 0.0f;
  for (int j = 0; j < S; j += 4) {
    const float4 ev = *reinterpret_cast<const float4*>(&e[h][j]);
    acc += ev.x * vp[(b*S+j+0)*DM + t];
    acc += ev.y * vp[(b*S+j+1)*DM + t];
    acc += ev.z * vp[(b*S+j+2)*DM + t];
    acc += ev.w * vp[(b*S+j+3)*DM + t];
  }
  oa[t] = acc / ssum[h];
  __syncthreads();
  float facc = bo[t];
  for (int d = 0; d < DM; ++d) facc += oa[d] * Wo[d*DM + t];
  out[bn*DM + t] = facc;
}

}  // namespace

extern "C" void kernel_launch(void* const* d_in, const int* in_sizes, int n_in,
                              void* d_out, int out_size, void* d_ws, size_t ws_size,
                              hipStream_t stream) {
  const float* xyz   = (const float*)d_in[0];
  const float* feats = (const float*)d_in[1];
  const float* alpha = (const float*)d_in[2];
  const float* beta  = (const float*)d_in[3];
  const float* W_t   = (const float*)d_in[4];
  const float* b_t   = (const float*)d_in[5];
  const float* bn_g  = (const float*)d_in[6];
  const float* bn_b  = (const float*)d_in[7];
  const float* Wq = (const float*)d_in[8];  const float* bq = (const float*)d_in[9];
  const float* Wk = (const float*)d_in[10]; const float* bk = (const float*)d_in[11];
  const float* Wv = (const float*)d_in[12]; const float* bv = (const float*)d_in[13];
  const float* Wo = (const float*)d_in[14]; const float* bo = (const float*)d_in[15];
  const float* Wp1= (const float*)d_in[16]; const float* bp1= (const float*)d_in[17];
  const float* Wp2= (const float*)d_in[18]; const float* bp2= (const float*)d_in[19];

  char* w = (char*)d_ws;
  int*    fps_i = (int*)   (w + 0);        // B*S ints            (4 KB)
  float*  nxyz  = (float*) (w + 4096);     // B*S*3               (12 KB)
  int*    knn_i = (int*)   (w + 16384);    // B*S*K ints          (128 KB)
  float*  meanb = (float*) (w + 147456);   // B*S*GC              (268 KB)
  float2* part  = (float2*)(w + 421888);   // B*S float2          (8 KB)
  float*  invs  = (float*) (w + 430080);   // B floats
  float*  vk    = (float*) (w + 430336);   // B*S*DM              (512 KB)
  float*  qbuf  = (float*) (w + 2003200);  // B*N*DM              (1 MB)
  float*  kpb   = (float*) (w + 3051776);  // B*S*DM              (512 KB)
  float*  vpb   = (float*) (w + 3576064);  // B*S*DM              (512 KB)
  float*  outf  = (float*)d_out;

  fps_kernel<<<B, 64, 0, stream>>>(xyz, fps_i, nxyz);
  knn_kernel<<<dim3(S/4, B), 256, 0, stream>>>(xyz, feats, nxyz, knn_i, meanb, part);
  stats_kernel<<<B, 64, 0, stream>>>(part, invs);
  transfer_kernel<<<B*S, 128, 0, stream>>>(feats, xyz, knn_i, fps_i, meanb, invs,
                                           alpha, beta, W_t, b_t, bn_g, bn_b,
                                           Wk, bk, Wv, bv, vk, kpb, vpb);
  interp_kernel<<<dim3(N/4, B), 256, 0, stream>>>(xyz, nxyz, vk, Wq, bq, qbuf);
  attn_kernel<<<B*N, 128, 0, stream>>>(xyz, nxyz, qbuf, kpb, vpb, Wp1, bp1, Wp2, bp2, Wo, bo, outf);
}

// Round 16
// 450.579 us; speedup vs baseline: 1.0754x; 1.0331x over previous
//
#include <hip/hip_runtime.h>
#include <math.h>

namespace {

constexpr int B  = 2;
constexpr int N  = 1024;
constexpr int CF = 64;    // C_FEAT
constexpr int S  = 512;
constexpr int K  = 32;
constexpr int DM = 128;   // D_MODEL
constexpr int NH = 4;
constexpr int DH = 32;
constexpr int GC = 67;    // grouped channels = CF + 3
constexpr int DIN = 131;  // GC + CF
constexpr int DPAD = 132; // padded row for float4 LDS reads
constexpr int EPAD = 516; // S+4: keeps e rows 16B-aligned for float4 reads

typedef float f2 __attribute__((ext_vector_type(2)));

__device__ inline float max3f(float a, float b, float c) { return fmaxf(fmaxf(a, b), c); }
__device__ inline unsigned min3u(unsigned a, unsigned b, unsigned c) { return min(min(a, b), c); }

// DPP helpers. Reduce-to-lane63 pattern: row_shr:1/2/4/8, row_bcast:15, row_bcast:31.
template <int CTRL>
__device__ inline float dpp_mov_f(float v) {
  // bound_ctrl=true: invalid lanes read 0 — valid identity for fmax of nonneg values.
  return __int_as_float(__builtin_amdgcn_update_dpp(0, __float_as_int(v), CTRL, 0xF, 0xF, true));
}
template <int CTRL>
__device__ inline unsigned dpp_mov_self_u(unsigned v) {
  // bound_ctrl=false with old=v: invalid lanes yield v — identity for min.
  return (unsigned)__builtin_amdgcn_update_dpp((int)v, (int)v, CTRL, 0xF, 0xF, false);
}

// ---------------- FPS (r10 exact): single wave per batch, pk-f32 update, two-pass DPP argmax ----------------
// Reduce-ledger winner (225us): two-pass f32 DPP (vs 250 u64 / 274 ballot / 298 bpermute).
__global__ void __launch_bounds__(64, 1)
fps_kernel(const float* __restrict__ xyz, int* __restrict__ fps_idx,
           float* __restrict__ new_xyz) {
  const int b = blockIdx.x;
  const int lane = threadIdx.x;           // 64 threads = 1 wave
  __shared__ __align__(16) float4 pts4[N];
  __shared__ int farhist[S];
  for (int p = lane; p < N; p += 64) {
    pts4[p] = make_float4(xyz[b*N*3 + p*3+0], xyz[b*N*3 + p*3+1], xyz[b*N*3 + p*3+2], 0.0f);
  }
  __syncthreads();
  f2 X[8], Y[8], Z[8];
  float dist[16];
  #pragma unroll
  for (int j = 0; j < 8; ++j) {
    const float4 a = pts4[(2*j)*64 + lane];
    const float4 c = pts4[(2*j+1)*64 + lane];
    X[j] = f2{a.x, c.x}; Y[j] = f2{a.y, c.y}; Z[j] = f2{a.z, c.z};
  }
  #pragma unroll
  for (int k = 0; k < 16; ++k) dist[k] = 1e10f;
  int far = 0;
  for (int s = 0; s < S; ++s) {
    if (lane == 0) farhist[s] = far;
    const float4 c = pts4[far];
    const f2 cx = f2{c.x, c.x}, cy = f2{c.y, c.y}, cz = f2{c.z, c.z};
    #pragma unroll
    for (int j = 0; j < 8; ++j) {
      const f2 dx = X[j] - cx, dy = Y[j] - cy, dz = Z[j] - cz;
      const f2 q = dx*dx + dy*dy + dz*dz;    // same per-element expression as reference
      dist[2*j]   = fminf(dist[2*j],   q.x);
      dist[2*j+1] = fminf(dist[2*j+1], q.y);
    }
    // pass 1: lane-local max via max3 tree (7 ops, depth 3)
    const float l0 = max3f(dist[0],  dist[1],  dist[2]);
    const float l1 = max3f(dist[3],  dist[4],  dist[5]);
    const float l2 = max3f(dist[6],  dist[7],  dist[8]);
    const float l3 = max3f(dist[9],  dist[10], dist[11]);
    const float l4 = max3f(dist[12], dist[13], dist[14]);
    float mv = fmaxf(max3f(l0, l1, l2), max3f(l3, l4, dist[15]));
    // wave64 max via DPP, result valid in lane 63
    mv = fmaxf(mv, dpp_mov_f<0x111>(mv));
    mv = fmaxf(mv, dpp_mov_f<0x112>(mv));
    mv = fmaxf(mv, dpp_mov_f<0x114>(mv));
    mv = fmaxf(mv, dpp_mov_f<0x118>(mv));
    mv = fmaxf(mv, dpp_mov_f<0x142>(mv));
    mv = fmaxf(mv, dpp_mov_f<0x143>(mv));
    const float maxv = __int_as_float(__builtin_amdgcn_readlane(__float_as_int(mv), 63));
    // pass 2: min index among exact maxima (min3 tree)
    unsigned cnd[16];
    #pragma unroll
    for (int k = 0; k < 16; ++k) {
      cnd[k] = (dist[k] == maxv) ? (unsigned)(k*64 + lane) : 0xFFFFFFFFu;
    }
    const unsigned u0 = min3u(cnd[0],  cnd[1],  cnd[2]);
    const unsigned u1 = min3u(cnd[3],  cnd[4],  cnd[5]);
    const unsigned u2 = min3u(cnd[6],  cnd[7],  cnd[8]);
    const unsigned u3 = min3u(cnd[9],  cnd[10], cnd[11]);
    const unsigned u4 = min3u(cnd[12], cnd[13], cnd[14]);
    unsigned cand = min(min3u(u0, u1, u2), min3u(u3, u4, cnd[15]));
    cand = min(cand, dpp_mov_self_u<0x111>(cand));
    cand = min(cand, dpp_mov_self_u<0x112>(cand));
    cand = min(cand, dpp_mov_self_u<0x114>(cand));
    cand = min(cand, dpp_mov_self_u<0x118>(cand));
    cand = min(cand, dpp_mov_self_u<0x142>(cand));
    cand = min(cand, dpp_mov_self_u<0x143>(cand));
    far = __builtin_amdgcn_readlane((int)cand, 63);
  }
  __syncthreads();
  // epilogue: write fps_idx and new_xyz from history
  for (int s = lane; s < S; s += 64) {
    const int f = farhist[s];
    const float4 c = pts4[f];
    fps_idx[b*S+s] = f;
    new_xyz[(b*S+s)*3+0] = c.x;
    new_xyz[(b*S+s)*3+1] = c.y;
    new_xyz[(b*S+s)*3+2] = c.z;
  }
}

// ---------------- KNN (K=32 of N=1024) + fused per-query group stats (r14) ----------------
__global__ void knn_kernel(const float* __restrict__ xyz, const float* __restrict__ feats,
                           const float* __restrict__ new_xyz, int* __restrict__ knn_idx,
                           float* __restrict__ mean_out, float2* __restrict__ partials) {
  const int b = blockIdx.y;
  const int tid = threadIdx.x;            // 256
  const int wave = tid >> 6, lane = tid & 63;
  const int s = blockIdx.x * 4 + wave;
  __shared__ float pts[N*3];
  __shared__ int sidx_s[4][K];
  for (int i = tid; i < N*3; i += 256) pts[i] = xyz[b*N*3 + i];
  __syncthreads();
  const float qx = new_xyz[(b*S+s)*3+0], qy = new_xyz[(b*S+s)*3+1], qz = new_xyz[(b*S+s)*3+2];
  const float qn = qx*qx + qy*qy + qz*qz;
  float d[16];
  #pragma unroll
  for (int j = 0; j < 16; ++j) {
    const int p = j*64 + lane;
    const float px = pts[p*3+0], py = pts[p*3+1], pz = pts[p*3+2];
    const float dot = qx*px + qy*py + qz*pz;
    const float pn  = px*px + py*py + pz*pz;
    d[j] = (-2.0f*dot + qn) + pn;          // reference's expanded form + add order
  }
  unsigned mask = 0xFFFFu;
  for (int k = 0; k < K; ++k) {
    float bv = INFINITY; int bj = 0;
    #pragma unroll
    for (int j = 0; j < 16; ++j) {
      if (((mask >> j) & 1u) && d[j] < bv) { bv = d[j]; bj = j; }
    }
    int bp = bj*64 + lane;
    #pragma unroll
    for (int m = 1; m < 64; m <<= 1) {
      const float ov = __shfl_xor(bv, m);
      const int   op = __shfl_xor(bp, m);
      if (ov < bv || (ov == bv && op < bp)) { bv = ov; bp = op; }
    }
    if (lane == 0) { knn_idx[(b*S+s)*K + k] = bp; sidx_s[wave][k] = bp; }
    if ((bp & 63) == lane) mask &= ~(1u << (bp >> 6));
  }
  // fused group stats for this query (wave-private; no block barrier)
  const int bs = b*S + s;
  float ls = 0.0f, lsq = 0.0f;
  float v[K];
  {
    const int c = lane;                    // channels 0..63 (< GC)
    float sum = 0.0f;
    #pragma unroll
    for (int k = 0; k < K; ++k) {
      const int p = sidx_s[wave][k];
      const float g = feats[(b*N+p)*CF + c];
      v[k] = g; sum += g;
    }
    const float mean = sum * (1.0f/K);
    mean_out[bs*GC + c] = mean;
    #pragma unroll
    for (int k = 0; k < K; ++k) {
      const float cc = v[k] - mean;
      ls += cc; lsq += cc*cc;
    }
  }
  if (lane < 3) {                          // channels 64..66 (xyz)
    const int c = CF + lane;
    float sum = 0.0f;
    #pragma unroll
    for (int k = 0; k < K; ++k) {
      const int p = sidx_s[wave][k];
      const float g = xyz[(b*N+p)*3 + lane];
      v[k] = g; sum += g;
    }
    const float mean = sum * (1.0f/K);
    mean_out[bs*GC + c] = mean;
    #pragma unroll
    for (int k = 0; k < K; ++k) {
      const float cc = v[k] - mean;
      ls += cc; lsq += cc*cc;
    }
  }
  #pragma unroll
  for (int m = 1; m < 64; m <<= 1) { ls += __shfl_xor(ls, m); lsq += __shfl_xor(lsq, m); }
  if (lane == 0) partials[bs] = make_float2(ls, lsq);
}

// ---------------- deterministic batch std (ddof=1), 64-lane double butterfly ----------------
__global__ void stats_kernel(const float2* __restrict__ partials, float* __restrict__ invstd) {
  const int b = blockIdx.x;
  const int lane = threadIdx.x;           // 64
  double su = 0.0, sq = 0.0;
  for (int i = lane; i < S; i += 64) {
    const float2 p = partials[b*S+i];
    su += (double)p.x; sq += (double)p.y;
  }
  #pragma unroll
  for (int m = 1; m < 64; m <<= 1) { su += __shfl_xor(su, m); sq += __shfl_xor(sq, m); }
  if (lane == 0) {
    const double nn = (double)S * K * GC;
    const double var = (sq - su*su/nn) / (nn - 1.0);
    invstd[b] = 1.0f / ((float)sqrt(var) + 1e-5f);
  }
}

// ---------------- transfer (r10 scalar acc): normalize+affine, 1x1 conv + BN + ReLU + max over K
//                  + fused k/v projections ----------------
__global__ void transfer_kernel(const float* __restrict__ feats, const float* __restrict__ xyz,
                                const int* __restrict__ knn_idx, const int* __restrict__ fps_idx,
                                const float* __restrict__ mean_in, const float* __restrict__ invstd,
                                const float* __restrict__ alpha, const float* __restrict__ beta,
                                const float* __restrict__ W_t, const float* __restrict__ b_t,
                                const float* __restrict__ bn_g, const float* __restrict__ bn_b,
                                const float* __restrict__ Wk, const float* __restrict__ bk,
                                const float* __restrict__ Wv, const float* __restrict__ bv,
                                float* __restrict__ v_k, float* __restrict__ kpb,
                                float* __restrict__ vpb) {
  const int bs = blockIdx.x;
  const int b = bs / S;
  const int t = threadIdx.x;              // 128
  __shared__ __align__(16) float np_s[K][DPAD];
  __shared__ float vrow[DM];
  __shared__ int sidx[K];
  __shared__ int sanchor;
  if (t < K) sidx[t] = knn_idx[bs*K + t];
  if (t == 0) sanchor = fps_idx[bs];
  __syncthreads();
  const float sinv = invstd[b];
  for (int k = 0; k < K; ++k) {
    const int p = sidx[k];
    for (int c = t; c < DPAD; c += 128) {
      float val = 0.0f;
      if (c < GC) {
        const float g = (c < CF) ? feats[(b*N+p)*CF + c] : xyz[(b*N+p)*3 + (c-CF)];
        val = (g - mean_in[bs*GC + c]) * sinv * alpha[c] + beta[c];
      } else if (c < DIN) {
        val = feats[(b*N+sanchor)*CF + (c - GC)];  // anchor feats, not normalized
      }
      np_s[k][c] = val;
    }
  }
  __syncthreads();
  float acc[K];
  const float bt = b_t[t];
  #pragma unroll
  for (int k = 0; k < K; ++k) acc[k] = bt;
  for (int d4 = 0; d4 < DPAD/4; ++d4) {
    const int d = d4*4;
    const float w0 = W_t[(d+0)*DM + t];
    const float w1 = W_t[(d+1)*DM + t];
    const float w2 = W_t[(d+2)*DM + t];
    const float w3 = (d+3 < DIN) ? W_t[(d+3)*DM + t] : 0.0f;
    #pragma unroll
    for (int k = 0; k < K; ++k) {
      const float4 f = *reinterpret_cast<const float4*>(&np_s[k][d]);
      acc[k] = acc[k] + f.x*w0 + f.y*w1 + f.z*w2 + f.w*w3;
    }
  }
  const float scale = bn_g[t] / sqrtf(1.0f + 1e-5f);
  const float shift = bn_b[t];
  float mx = -INFINITY;
  #pragma unroll
  for (int k = 0; k < K; ++k) {
    const float y = fmaxf(acc[k]*scale + shift, 0.0f);
    mx = fmaxf(mx, y);
  }
  v_k[bs*DM + t] = mx;
  vrow[t] = mx;
  __syncthreads();
  // fused k/v projections: same per-channel serial-d accumulation order as before
  float acck = bk[t], accv = bv[t];
  for (int d = 0; d < DM; ++d) {
    const float f = vrow[d];
    acck += f * Wk[d*DM + t];
    accv += f * Wv[d*DM + t];
  }
  kpb[bs*DM + t] = acck;
  vpb[bs*DM + t] = accv;
}

// ---------------- 3-NN inverse-distance interpolation + fused q projection ----------------
__global__ void interp_kernel(const float* __restrict__ xyz, const float* __restrict__ new_xyz,
                              const float* __restrict__ v_k, const float* __restrict__ Wq,
                              const float* __restrict__ bq, float* __restrict__ qbuf) {
  const int b = blockIdx.y;
  const int tid = threadIdx.x;            // 256
  const int wave = tid >> 6, lane = tid & 63;
  const int n = blockIdx.x*4 + wave;
  __shared__ float pts[S*3];
  __shared__ float vqs[4][DM];
  for (int i = tid; i < S*3; i += 256) pts[i] = new_xyz[b*S*3 + i];
  __syncthreads();
  const float qx = xyz[(b*N+n)*3+0], qy = xyz[(b*N+n)*3+1], qz = xyz[(b*N+n)*3+2];
  const float qn = qx*qx + qy*qy + qz*qz;
  float d[8];
  #pragma unroll
  for (int j = 0; j < 8; ++j) {
    const int p = j*64 + lane;
    const float px = pts[p*3+0], py = pts[p*3+1], pz = pts[p*3+2];
    const float dot = qx*px + qy*py + qz*pz;
    const float pn  = px*px + py*py + pz*pz;
    d[j] = (-2.0f*dot + qn) + pn;
  }
  unsigned mask = 0xFFu;
  float sd[3]; int sp[3];
  #pragma unroll
  for (int k = 0; k < 3; ++k) {
    float bv = INFINITY; int bj = 0;
    #pragma unroll
    for (int j = 0; j < 8; ++j) {
      if (((mask >> j) & 1u) && d[j] < bv) { bv = d[j]; bj = j; }
    }
    int bp = bj*64 + lane;
    #pragma unroll
    for (int m = 1; m < 64; m <<= 1) {
      const float ov = __shfl_xor(bv, m);
      const int   op = __shfl_xor(bp, m);
      if (ov < bv || (ov == bv && op < bp)) { bv = ov; bp = op; }
    }
    sd[k] = bv; sp[k] = bp;
    if ((bp & 63) == lane) mask &= ~(1u << (bp >> 6));
  }
  float w0 = 1.0f / fmaxf(sd[0], 1e-10f);
  float w1 = 1.0f / fmaxf(sd[1], 1e-10f);
  float w2 = 1.0f / fmaxf(sd[2], 1e-10f);
  const float wsum = w0 + w1 + w2;
  w0 /= wsum; w1 /= wsum; w2 /= wsum;
  const float* vk0 = v_k + (b*S + sp[0])*DM;
  const float* vk1 = v_k + (b*S + sp[1])*DM;
  const float* vk2 = v_k + (b*S + sp[2])*DM;
  #pragma unroll
  for (int c = lane; c < DM; c += 64) {
    vqs[wave][c] = w0*vk0[c] + w1*vk1[c] + w2*vk2[c];
  }
  __syncthreads();
  // fused q projection: each lane owns channels lane and lane+64 of its wave's row
  const float* row = vqs[wave];
  #pragma unroll
  for (int half = 0; half < 2; ++half) {
    const int c = lane + half*64;
    float acc = bq[c];
    for (int d = 0; d < DM; ++d) acc += row[d] * Wq[d*DM + c];
    qbuf[(b*N+n)*DM + c] = acc;
  }
}

// ---------------- cross-attention (r10 j-outer scalar RPE) + output projection ----------------
__global__ void attn_kernel(const float* __restrict__ xyz, const float* __restrict__ new_xyz,
                            const float* __restrict__ qb, const float* __restrict__ kp,
                            const float* __restrict__ vp, const float* __restrict__ Wp1,
                            const float* __restrict__ bp1, const float* __restrict__ Wp2,
                            const float* __restrict__ bp2, const float* __restrict__ Wo,
                            const float* __restrict__ bo, float* __restrict__ out) {
  const int bn = blockIdx.x;              // b*N + n
  const int b = bn / N;
  const int t = threadIdx.x;              // 128
  __shared__ __align__(16) float e[NH][EPAD];
  __shared__ float qn_s[DM];
  __shared__ float oa[DM];
  __shared__ float ssum[NH];
  qn_s[t] = qb[bn*DM + t];
  __syncthreads();
  const float qx = xyz[bn*3+0], qy = xyz[bn*3+1], qz = xyz[bn*3+2];
  const float rs = 0.17677669529663687f;  // 1/sqrt(32)
  for (int j = t; j < S; j += 128) {
    const float px = new_xyz[(b*S+j)*3+0], py = new_xyz[(b*S+j)*3+1], pz = new_xyz[(b*S+j)*3+2];
    const float rx = qx-px, ry = qy-py, rz = qz-pz;
    float r0 = bp2[0], r1 = bp2[1], r2 = bp2[2], r3 = bp2[3];
    for (int m = 0; m < DM; ++m) {
      float hm = rx*Wp1[m] + ry*Wp1[DM+m] + rz*Wp1[2*DM+m] + bp1[m];
      hm = fmaxf(hm, 0.0f);
      r0 += hm*Wp2[m*NH+0]; r1 += hm*Wp2[m*NH+1];
      r2 += hm*Wp2[m*NH+2]; r3 += hm*Wp2[m*NH+3];
    }
    const float rpe[NH] = {r0, r1, r2, r3};
    #pragma unroll
    for (int h = 0; h < NH; ++h) {
      const float* kr = kp + (b*S+j)*DM + h*DH;
      const float* qr = qn_s + h*DH;
      float acc = 0.0f;
      #pragma unroll
      for (int dd = 0; dd < DH; ++dd) acc += qr[dd]*kr[dd];
      e[h][j] = acc*rs + rpe[h];
    }
  }
  __syncthreads();
  const int h = t >> 5, g = t & 31;       // 32 threads per head
  float mx = -INFINITY;
  for (int j = g; j < S; j += 32) mx = fmaxf(mx, e[h][j]);
  #pragma unroll
  for (int m = 16; m >= 1; m >>= 1) mx = fmaxf(mx, __shfl_xor(mx, m));
  float sum = 0.0f;
  for (int j = g; j < S; j += 32) { const float ex = expf(e[h][j]-mx); e[h][j] = ex; sum += ex; }
  #pragma unroll
  for (int m = 16; m >= 1; m >>= 1) sum += __shfl_xor(sum, m);
  if (g == 0) ssum[h] = sum;
  __syncthreads();
  float acc = 0.0f;
  for (int j = 0; j < S; j += 4) {
    const float4 ev = *reinterpret_cast<const float4*>(&e[h][j]);
    acc += ev.x * vp[(b*S+j+0)*DM + t];
    acc += ev.y * vp[(b*S+j+1)*DM + t];
    acc += ev.z * vp[(b*S+j+2)*DM + t];
    acc += ev.w * vp[(b*S+j+3)*DM + t];
  }
  oa[t] = acc / ssum[h];
  __syncthreads();
  float facc = bo[t];
  for (int d = 0; d < DM; ++d) facc += oa[d] * Wo[d*DM + t];
  out[bn*DM + t] = facc;
}

}  // namespace

extern "C" void kernel_launch(void* const* d_in, const int* in_sizes, int n_in,
                              void* d_out, int out_size, void* d_ws, size_t ws_size,
                              hipStream_t stream) {
  const float* xyz   = (const float*)d_in[0];
  const float* feats = (const float*)d_in[1];
  const float* alpha = (const float*)d_in[2];
  const float* beta  = (const float*)d_in[3];
  const float* W_t   = (const float*)d_in[4];
  const float* b_t   = (const float*)d_in[5];
  const float* bn_g  = (const float*)d_in[6];
  const float* bn_b  = (const float*)d_in[7];
  const float* Wq = (const float*)d_in[8];  const float* bq = (const float*)d_in[9];
  const float* Wk = (const float*)d_in[10]; const float* bk = (const float*)d_in[11];
  const float* Wv = (const float*)d_in[12]; const float* bv = (const float*)d_in[13];
  const float* Wo = (const float*)d_in[14]; const float* bo = (const float*)d_in[15];
  const float* Wp1= (const float*)d_in[16]; const float* bp1= (const float*)d_in[17];
  const float* Wp2= (const float*)d_in[18]; const float* bp2= (const float*)d_in[19];

  char* w = (char*)d_ws;
  int*    fps_i = (int*)   (w + 0);        // B*S ints            (4 KB)
  float*  nxyz  = (float*) (w + 4096);     // B*S*3               (12 KB)
  int*    knn_i = (int*)   (w + 16384);    // B*S*K ints          (128 KB)
  float*  meanb = (float*) (w + 147456);   // B*S*GC              (268 KB)
  float2* part  = (float2*)(w + 421888);   // B*S float2          (8 KB)
  float*  invs  = (float*) (w + 430080);   // B floats
  float*  vk    = (float*) (w + 430336);   // B*S*DM              (512 KB)
  float*  qbuf  = (float*) (w + 2003200);  // B*N*DM              (1 MB)
  float*  kpb   = (float*) (w + 3051776);  // B*S*DM              (512 KB)
  float*  vpb   = (float*) (w + 3576064);  // B*S*DM              (512 KB)
  float*  outf  = (float*)d_out;

  fps_kernel<<<B, 64, 0, stream>>>(xyz, fps_i, nxyz);
  knn_kernel<<<dim3(S/4, B), 256, 0, stream>>>(xyz, feats, nxyz, knn_i, meanb, part);
  stats_kernel<<<B, 64, 0, stream>>>(part, invs);
  transfer_kernel<<<B*S, 128, 0, stream>>>(feats, xyz, knn_i, fps_i, meanb, invs,
                                           alpha, beta, W_t, b_t, bn_g, bn_b,
                                           Wk, bk, Wv, bv, vk, kpb, vpb);
  interp_kernel<<<dim3(N/4, B), 256, 0, stream>>>(xyz, nxyz, vk, Wq, bq, qbuf);
  attn_kernel<<<B*N, 128, 0, stream>>>(xyz, nxyz, qbuf, kpb, vpb, Wp1, bp1, Wp2, bp2, Wo, bo, outf);
}

// Round 17
// 447.979 us; speedup vs baseline: 1.0816x; 1.0058x over previous
//
#include <hip/hip_runtime.h>
#include <math.h>

namespace {

constexpr int B  = 2;
constexpr int N  = 1024;
constexpr int CF = 64;    // C_FEAT
constexpr int S  = 512;
constexpr int K  = 32;
constexpr int DM = 128;   // D_MODEL
constexpr int NH = 4;
constexpr int DH = 32;
constexpr int GC = 67;    // grouped channels = CF + 3
constexpr int DIN = 131;  // GC + CF
constexpr int DPAD = 132; // padded row for float4 LDS reads
constexpr int EPAD = 516; // S+4: keeps e rows 16B-aligned for float4 reads

typedef float f2 __attribute__((ext_vector_type(2)));

__device__ inline float max3f(float a, float b, float c) { return fmaxf(fmaxf(a, b), c); }
__device__ inline unsigned min3u(unsigned a, unsigned b, unsigned c) { return min(min(a, b), c); }

// DPP helpers. Reduce-to-lane63 pattern: row_shr:1/2/4/8, row_bcast:15, row_bcast:31.
template <int CTRL>
__device__ inline float dpp_mov_f(float v) {
  // bound_ctrl=true: invalid lanes read 0 — valid identity for fmax of nonneg values.
  return __int_as_float(__builtin_amdgcn_update_dpp(0, __float_as_int(v), CTRL, 0xF, 0xF, true));
}
template <int CTRL>
__device__ inline unsigned dpp_mov_self_u(unsigned v) {
  // bound_ctrl=false with old=v: invalid lanes yield v — identity for min.
  return (unsigned)__builtin_amdgcn_update_dpp((int)v, (int)v, CTRL, 0xF, 0xF, false);
}

// ---------------- FPS (r10 exact): single wave per batch, pk-f32 update, two-pass DPP argmax ----------------
__global__ void __launch_bounds__(64, 1)
fps_kernel(const float* __restrict__ xyz, int* __restrict__ fps_idx,
           float* __restrict__ new_xyz) {
  const int b = blockIdx.x;
  const int lane = threadIdx.x;           // 64 threads = 1 wave
  __shared__ __align__(16) float4 pts4[N];
  __shared__ int farhist[S];
  for (int p = lane; p < N; p += 64) {
    pts4[p] = make_float4(xyz[b*N*3 + p*3+0], xyz[b*N*3 + p*3+1], xyz[b*N*3 + p*3+2], 0.0f);
  }
  __syncthreads();
  f2 X[8], Y[8], Z[8];
  float dist[16];
  #pragma unroll
  for (int j = 0; j < 8; ++j) {
    const float4 a = pts4[(2*j)*64 + lane];
    const float4 c = pts4[(2*j+1)*64 + lane];
    X[j] = f2{a.x, c.x}; Y[j] = f2{a.y, c.y}; Z[j] = f2{a.z, c.z};
  }
  #pragma unroll
  for (int k = 0; k < 16; ++k) dist[k] = 1e10f;
  int far = 0;
  for (int s = 0; s < S; ++s) {
    if (lane == 0) farhist[s] = far;
    const float4 c = pts4[far];
    const f2 cx = f2{c.x, c.x}, cy = f2{c.y, c.y}, cz = f2{c.z, c.z};
    #pragma unroll
    for (int j = 0; j < 8; ++j) {
      const f2 dx = X[j] - cx, dy = Y[j] - cy, dz = Z[j] - cz;
      const f2 q = dx*dx + dy*dy + dz*dz;    // same per-element expression as reference
      dist[2*j]   = fminf(dist[2*j],   q.x);
      dist[2*j+1] = fminf(dist[2*j+1], q.y);
    }
    const float l0 = max3f(dist[0],  dist[1],  dist[2]);
    const float l1 = max3f(dist[3],  dist[4],  dist[5]);
    const float l2 = max3f(dist[6],  dist[7],  dist[8]);
    const float l3 = max3f(dist[9],  dist[10], dist[11]);
    const float l4 = max3f(dist[12], dist[13], dist[14]);
    float mv = fmaxf(max3f(l0, l1, l2), max3f(l3, l4, dist[15]));
    mv = fmaxf(mv, dpp_mov_f<0x111>(mv));
    mv = fmaxf(mv, dpp_mov_f<0x112>(mv));
    mv = fmaxf(mv, dpp_mov_f<0x114>(mv));
    mv = fmaxf(mv, dpp_mov_f<0x118>(mv));
    mv = fmaxf(mv, dpp_mov_f<0x142>(mv));
    mv = fmaxf(mv, dpp_mov_f<0x143>(mv));
    const float maxv = __int_as_float(__builtin_amdgcn_readlane(__float_as_int(mv), 63));
    unsigned cnd[16];
    #pragma unroll
    for (int k = 0; k < 16; ++k) {
      cnd[k] = (dist[k] == maxv) ? (unsigned)(k*64 + lane) : 0xFFFFFFFFu;
    }
    const unsigned u0 = min3u(cnd[0],  cnd[1],  cnd[2]);
    const unsigned u1 = min3u(cnd[3],  cnd[4],  cnd[5]);
    const unsigned u2 = min3u(cnd[6],  cnd[7],  cnd[8]);
    const unsigned u3 = min3u(cnd[9],  cnd[10], cnd[11]);
    const unsigned u4 = min3u(cnd[12], cnd[13], cnd[14]);
    unsigned cand = min(min3u(u0, u1, u2), min3u(u3, u4, cnd[15]));
    cand = min(cand, dpp_mov_self_u<0x111>(cand));
    cand = min(cand, dpp_mov_self_u<0x112>(cand));
    cand = min(cand, dpp_mov_self_u<0x114>(cand));
    cand = min(cand, dpp_mov_self_u<0x118>(cand));
    cand = min(cand, dpp_mov_self_u<0x142>(cand));
    cand = min(cand, dpp_mov_self_u<0x143>(cand));
    far = __builtin_amdgcn_readlane((int)cand, 63);
  }
  __syncthreads();
  for (int s = lane; s < S; s += 64) {
    const int f = farhist[s];
    const float4 c = pts4[f];
    fps_idx[b*S+s] = f;
    new_xyz[(b*S+s)*3+0] = c.x;
    new_xyz[(b*S+s)*3+1] = c.y;
    new_xyz[(b*S+s)*3+2] = c.z;
  }
}

// ---------------- KNN (K=32 of N=1024) + fused per-query group stats (r14) ----------------
__global__ void knn_kernel(const float* __restrict__ xyz, const float* __restrict__ feats,
                           const float* __restrict__ new_xyz, int* __restrict__ knn_idx,
                           float* __restrict__ mean_out, float2* __restrict__ partials) {
  const int b = blockIdx.y;
  const int tid = threadIdx.x;            // 256
  const int wave = tid >> 6, lane = tid & 63;
  const int s = blockIdx.x * 4 + wave;
  __shared__ float pts[N*3];
  __shared__ int sidx_s[4][K];
  for (int i = tid; i < N*3; i += 256) pts[i] = xyz[b*N*3 + i];
  __syncthreads();
  const float qx = new_xyz[(b*S+s)*3+0], qy = new_xyz[(b*S+s)*3+1], qz = new_xyz[(b*S+s)*3+2];
  const float qn = qx*qx + qy*qy + qz*qz;
  float d[16];
  #pragma unroll
  for (int j = 0; j < 16; ++j) {
    const int p = j*64 + lane;
    const float px = pts[p*3+0], py = pts[p*3+1], pz = pts[p*3+2];
    const float dot = qx*px + qy*py + qz*pz;
    const float pn  = px*px + py*py + pz*pz;
    d[j] = (-2.0f*dot + qn) + pn;          // reference's expanded form + add order
  }
  unsigned mask = 0xFFFFu;
  for (int k = 0; k < K; ++k) {
    float bv = INFINITY; int bj = 0;
    #pragma unroll
    for (int j = 0; j < 16; ++j) {
      if (((mask >> j) & 1u) && d[j] < bv) { bv = d[j]; bj = j; }
    }
    int bp = bj*64 + lane;
    #pragma unroll
    for (int m = 1; m < 64; m <<= 1) {
      const float ov = __shfl_xor(bv, m);
      const int   op = __shfl_xor(bp, m);
      if (ov < bv || (ov == bv && op < bp)) { bv = ov; bp = op; }
    }
    if (lane == 0) { knn_idx[(b*S+s)*K + k] = bp; sidx_s[wave][k] = bp; }
    if ((bp & 63) == lane) mask &= ~(1u << (bp >> 6));
  }
  const int bs = b*S + s;
  float ls = 0.0f, lsq = 0.0f;
  float v[K];
  {
    const int c = lane;                    // channels 0..63 (< GC)
    float sum = 0.0f;
    #pragma unroll
    for (int k = 0; k < K; ++k) {
      const int p = sidx_s[wave][k];
      const float g = feats[(b*N+p)*CF + c];
      v[k] = g; sum += g;
    }
    const float mean = sum * (1.0f/K);
    mean_out[bs*GC + c] = mean;
    #pragma unroll
    for (int k = 0; k < K; ++k) {
      const float cc = v[k] - mean;
      ls += cc; lsq += cc*cc;
    }
  }
  if (lane < 3) {                          // channels 64..66 (xyz)
    const int c = CF + lane;
    float sum = 0.0f;
    #pragma unroll
    for (int k = 0; k < K; ++k) {
      const int p = sidx_s[wave][k];
      const float g = xyz[(b*N+p)*3 + lane];
      v[k] = g; sum += g;
    }
    const float mean = sum * (1.0f/K);
    mean_out[bs*GC + c] = mean;
    #pragma unroll
    for (int k = 0; k < K; ++k) {
      const float cc = v[k] - mean;
      ls += cc; lsq += cc*cc;
    }
  }
  #pragma unroll
  for (int m = 1; m < 64; m <<= 1) { ls += __shfl_xor(ls, m); lsq += __shfl_xor(lsq, m); }
  if (lane == 0) partials[bs] = make_float2(ls, lsq);
}

// ---------------- deterministic batch std (ddof=1), 64-lane double butterfly ----------------
__global__ void stats_kernel(const float2* __restrict__ partials, float* __restrict__ invstd) {
  const int b = blockIdx.x;
  const int lane = threadIdx.x;           // 64
  double su = 0.0, sq = 0.0;
  for (int i = lane; i < S; i += 64) {
    const float2 p = partials[b*S+i];
    su += (double)p.x; sq += (double)p.y;
  }
  #pragma unroll
  for (int m = 1; m < 64; m <<= 1) { su += __shfl_xor(su, m); sq += __shfl_xor(sq, m); }
  if (lane == 0) {
    const double nn = (double)S * K * GC;
    const double var = (sq - su*su/nn) / (nn - 1.0);
    invstd[b] = 1.0f / ((float)sqrt(var) + 1e-5f);
  }
}

// ---------------- transfer (r10 scalar acc) + fused k/v projections ----------------
__global__ void transfer_kernel(const float* __restrict__ feats, const float* __restrict__ xyz,
                                const int* __restrict__ knn_idx, const int* __restrict__ fps_idx,
                                const float* __restrict__ mean_in, const float* __restrict__ invstd,
                                const float* __restrict__ alpha, const float* __restrict__ beta,
                                const float* __restrict__ W_t, const float* __restrict__ b_t,
                                const float* __restrict__ bn_g, const float* __restrict__ bn_b,
                                const float* __restrict__ Wk, const float* __restrict__ bk,
                                const float* __restrict__ Wv, const float* __restrict__ bv,
                                float* __restrict__ v_k, float* __restrict__ kpb,
                                float* __restrict__ vpb) {
  const int bs = blockIdx.x;
  const int b = bs / S;
  const int t = threadIdx.x;              // 128
  __shared__ __align__(16) float np_s[K][DPAD];
  __shared__ float vrow[DM];
  __shared__ int sidx[K];
  __shared__ int sanchor;
  if (t < K) sidx[t] = knn_idx[bs*K + t];
  if (t == 0) sanchor = fps_idx[bs];
  __syncthreads();
  const float sinv = invstd[b];
  for (int k = 0; k < K; ++k) {
    const int p = sidx[k];
    for (int c = t; c < DPAD; c += 128) {
      float val = 0.0f;
      if (c < GC) {
        const float g = (c < CF) ? feats[(b*N+p)*CF + c] : xyz[(b*N+p)*3 + (c-CF)];
        val = (g - mean_in[bs*GC + c]) * sinv * alpha[c] + beta[c];
      } else if (c < DIN) {
        val = feats[(b*N+sanchor)*CF + (c - GC)];  // anchor feats, not normalized
      }
      np_s[k][c] = val;
    }
  }
  __syncthreads();
  float acc[K];
  const float bt = b_t[t];
  #pragma unroll
  for (int k = 0; k < K; ++k) acc[k] = bt;
  for (int d4 = 0; d4 < DPAD/4; ++d4) {
    const int d = d4*4;
    const float w0 = W_t[(d+0)*DM + t];
    const float w1 = W_t[(d+1)*DM + t];
    const float w2 = W_t[(d+2)*DM + t];
    const float w3 = (d+3 < DIN) ? W_t[(d+3)*DM + t] : 0.0f;
    #pragma unroll
    for (int k = 0; k < K; ++k) {
      const float4 f = *reinterpret_cast<const float4*>(&np_s[k][d]);
      acc[k] = acc[k] + f.x*w0 + f.y*w1 + f.z*w2 + f.w*w3;
    }
  }
  const float scale = bn_g[t] / sqrtf(1.0f + 1e-5f);
  const float shift = bn_b[t];
  float mx = -INFINITY;
  #pragma unroll
  for (int k = 0; k < K; ++k) {
    const float y = fmaxf(acc[k]*scale + shift, 0.0f);
    mx = fmaxf(mx, y);
  }
  v_k[bs*DM + t] = mx;
  vrow[t] = mx;
  __syncthreads();
  float acck = bk[t], accv = bv[t];
  for (int d = 0; d < DM; ++d) {
    const float f = vrow[d];
    acck += f * Wk[d*DM + t];
    accv += f * Wv[d*DM + t];
  }
  kpb[bs*DM + t] = acck;
  vpb[bs*DM + t] = accv;
}

// ---------------- 3-NN inverse-distance interpolation + fused q projection ----------------
__global__ void interp_kernel(const float* __restrict__ xyz, const float* __restrict__ new_xyz,
                              const float* __restrict__ v_k, const float* __restrict__ Wq,
                              const float* __restrict__ bq, float* __restrict__ qbuf) {
  const int b = blockIdx.y;
  const int tid = threadIdx.x;            // 256
  const int wave = tid >> 6, lane = tid & 63;
  const int n = blockIdx.x*4 + wave;
  __shared__ float pts[S*3];
  __shared__ float vqs[4][DM];
  for (int i = tid; i < S*3; i += 256) pts[i] = new_xyz[b*S*3 + i];
  __syncthreads();
  const float qx = xyz[(b*N+n)*3+0], qy = xyz[(b*N+n)*3+1], qz = xyz[(b*N+n)*3+2];
  const float qn = qx*qx + qy*qy + qz*qz;
  float d[8];
  #pragma unroll
  for (int j = 0; j < 8; ++j) {
    const int p = j*64 + lane;
    const float px = pts[p*3+0], py = pts[p*3+1], pz = pts[p*3+2];
    const float dot = qx*px + qy*py + qz*pz;
    const float pn  = px*px + py*py + pz*pz;
    d[j] = (-2.0f*dot + qn) + pn;
  }
  unsigned mask = 0xFFu;
  float sd[3]; int sp[3];
  #pragma unroll
  for (int k = 0; k < 3; ++k) {
    float bv = INFINITY; int bj = 0;
    #pragma unroll
    for (int j = 0; j < 8; ++j) {
      if (((mask >> j) & 1u) && d[j] < bv) { bv = d[j]; bj = j; }
    }
    int bp = bj*64 + lane;
    #pragma unroll
    for (int m = 1; m < 64; m <<= 1) {
      const float ov = __shfl_xor(bv, m);
      const int   op = __shfl_xor(bp, m);
      if (ov < bv || (ov == bv && op < bp)) { bv = ov; bp = op; }
    }
    sd[k] = bv; sp[k] = bp;
    if ((bp & 63) == lane) mask &= ~(1u << (bp >> 6));
  }
  float w0 = 1.0f / fmaxf(sd[0], 1e-10f);
  float w1 = 1.0f / fmaxf(sd[1], 1e-10f);
  float w2 = 1.0f / fmaxf(sd[2], 1e-10f);
  const float wsum = w0 + w1 + w2;
  w0 /= wsum; w1 /= wsum; w2 /= wsum;
  const float* vk0 = v_k + (b*S + sp[0])*DM;
  const float* vk1 = v_k + (b*S + sp[1])*DM;
  const float* vk2 = v_k + (b*S + sp[2])*DM;
  #pragma unroll
  for (int c = lane; c < DM; c += 64) {
    vqs[wave][c] = w0*vk0[c] + w1*vk1[c] + w2*vk2[c];
  }
  __syncthreads();
  const float* row = vqs[wave];
  #pragma unroll
  for (int half = 0; half < 2; ++half) {
    const int c = lane + half*64;
    float acc = bq[c];
    for (int d = 0; d < DM; ++d) acc += row[d] * Wq[d*DM + c];
    qbuf[(b*N+n)*DM + c] = acc;
  }
}

// ---------------- cross-attention: RPE weights LDS-staged, float4 K loads ----------------
__global__ void attn_kernel(const float* __restrict__ xyz, const float* __restrict__ new_xyz,
                            const float* __restrict__ qb, const float* __restrict__ kp,
                            const float* __restrict__ vp, const float* __restrict__ Wp1,
                            const float* __restrict__ bp1, const float* __restrict__ Wp2,
                            const float* __restrict__ bp2, const float* __restrict__ Wo,
                            const float* __restrict__ bo, float* __restrict__ out) {
  const int bn = blockIdx.x;              // b*N + n
  const int b = bn / N;
  const int t = threadIdx.x;              // 128
  __shared__ __align__(16) float e[NH][EPAD];
  __shared__ float qn_s[DM];
  __shared__ float oa[DM];
  __shared__ float ssum[NH];
  // LDS-staged RPE weights: kills per-iteration global loads (all 2048 blocks
  // were re-fetching the same lines every m -> latency/contention bound,
  // VALUBusy 2.3%). LDS broadcast reads are cheap and block-local.
  __shared__ float wp1a[DM], wp1b[DM], wp1c[DM], bp1s[DM];
  __shared__ float wp2s[DM*NH];
  qn_s[t] = qb[bn*DM + t];
  wp1a[t] = Wp1[t];
  wp1b[t] = Wp1[DM + t];
  wp1c[t] = Wp1[2*DM + t];
  bp1s[t] = bp1[t];
  #pragma unroll
  for (int i = 0; i < NH; ++i) wp2s[i*128 + t] = Wp2[i*128 + t];
  __syncthreads();
  const float qx = xyz[bn*3+0], qy = xyz[bn*3+1], qz = xyz[bn*3+2];
  const float rs = 0.17677669529663687f;  // 1/sqrt(32)
  for (int j = t; j < S; j += 128) {
    const float px = new_xyz[(b*S+j)*3+0], py = new_xyz[(b*S+j)*3+1], pz = new_xyz[(b*S+j)*3+2];
    const float rx = qx-px, ry = qy-py, rz = qz-pz;
    float r0 = bp2[0], r1 = bp2[1], r2 = bp2[2], r3 = bp2[3];
    for (int m = 0; m < DM; ++m) {
      float hm = rx*wp1a[m] + ry*wp1b[m] + rz*wp1c[m] + bp1s[m];
      hm = fmaxf(hm, 0.0f);
      r0 += hm*wp2s[m*NH+0]; r1 += hm*wp2s[m*NH+1];
      r2 += hm*wp2s[m*NH+2]; r3 += hm*wp2s[m*NH+3];
    }
    const float rpe[NH] = {r0, r1, r2, r3};
    #pragma unroll
    for (int h = 0; h < NH; ++h) {
      const float4* kr4 = reinterpret_cast<const float4*>(kp + (b*S+j)*DM + h*DH);
      const float* qr = qn_s + h*DH;
      float acc = 0.0f;
      #pragma unroll
      for (int dd = 0; dd < 8; ++dd) {
        const float4 kv = kr4[dd];
        acc += qr[dd*4+0]*kv.x + qr[dd*4+1]*kv.y + qr[dd*4+2]*kv.z + qr[dd*4+3]*kv.w;
      }
      e[h][j] = acc*rs + rpe[h];
    }
  }
  __syncthreads();
  const int h = t >> 5, g = t & 31;       // 32 threads per head
  float mx = -INFINITY;
  for (int j = g; j < S; j += 32) mx = fmaxf(mx, e[h][j]);
  #pragma unroll
  for (int m = 16; m >= 1; m >>= 1) mx = fmaxf(mx, __shfl_xor(mx, m));
  float sum = 0.0f;
  for (int j = g; j < S; j += 32) { const float ex = expf(e[h][j]-mx); e[h][j] = ex; sum += ex; }
  #pragma unroll
  for (int m = 16; m >= 1; m >>= 1) sum += __shfl_xor(sum, m);
  if (g == 0) ssum[h] = sum;
  __syncthreads();
  float acc = 0.0f;
  for (int j = 0; j < S; j += 4) {
    const float4 ev = *reinterpret_cast<const float4*>(&e[h][j]);
    acc += ev.x * vp[(b*S+j+0)*DM + t];
    acc += ev.y * vp[(b*S+j+1)*DM + t];
    acc += ev.z * vp[(b*S+j+2)*DM + t];
    acc += ev.w * vp[(b*S+j+3)*DM + t];
  }
  oa[t] = acc / ssum[h];
  __syncthreads();
  float facc = bo[t];
  for (int d = 0; d < DM; ++d) facc += oa[d] * Wo[d*DM + t];
  out[bn*DM + t] = facc;
}

}  // namespace

extern "C" void kernel_launch(void* const* d_in, const int* in_sizes, int n_in,
                              void* d_out, int out_size, void* d_ws, size_t ws_size,
                              hipStream_t stream) {
  const float* xyz   = (const float*)d_in[0];
  const float* feats = (const float*)d_in[1];
  const float* alpha = (const float*)d_in[2];
  const float* beta  = (const float*)d_in[3];
  const float* W_t   = (const float*)d_in[4];
  const float* b_t   = (const float*)d_in[5];
  const float* bn_g  = (const float*)d_in[6];
  const float* bn_b  = (const float*)d_in[7];
  const float* Wq = (const float*)d_in[8];  const float* bq = (const float*)d_in[9];
  const float* Wk = (const float*)d_in[10]; const float* bk = (const float*)d_in[11];
  const float* Wv = (const float*)d_in[12]; const float* bv = (const float*)d_in[13];
  const float* Wo = (const float*)d_in[14]; const float* bo = (const float*)d_in[15];
  const float* Wp1= (const float*)d_in[16]; const float* bp1= (const float*)d_in[17];
  const float* Wp2= (const float*)d_in[18]; const float* bp2= (const float*)d_in[19];

  char* w = (char*)d_ws;
  int*    fps_i = (int*)   (w + 0);        // B*S ints            (4 KB)
  float*  nxyz  = (float*) (w + 4096);     // B*S*3               (12 KB)
  int*    knn_i = (int*)   (w + 16384);    // B*S*K ints          (128 KB)
  float*  meanb = (float*) (w + 147456);   // B*S*GC              (268 KB)
  float2* part  = (float2*)(w + 421888);   // B*S float2          (8 KB)
  float*  invs  = (float*) (w + 430080);   // B floats
  float*  vk    = (float*) (w + 430336);   // B*S*DM              (512 KB)
  float*  qbuf  = (float*) (w + 2003200);  // B*N*DM              (1 MB)
  float*  kpb   = (float*) (w + 3051776);  // B*S*DM              (512 KB)
  float*  vpb   = (float*) (w + 3576064);  // B*S*DM              (512 KB)
  float*  outf  = (float*)d_out;

  fps_kernel<<<B, 64, 0, stream>>>(xyz, fps_i, nxyz);
  knn_kernel<<<dim3(S/4, B), 256, 0, stream>>>(xyz, feats, nxyz, knn_i, meanb, part);
  stats_kernel<<<B, 64, 0, stream>>>(part, invs);
  transfer_kernel<<<B*S, 128, 0, stream>>>(feats, xyz, knn_i, fps_i, meanb, invs,
                                           alpha, beta, W_t, b_t, bn_g, bn_b,
                                           Wk, bk, Wv, bv, vk, kpb, vpb);
  interp_kernel<<<dim3(N/4, B), 256, 0, stream>>>(xyz, nxyz, vk, Wq, bq, qbuf);
  attn_kernel<<<B*N, 128, 0, stream>>>(xyz, nxyz, qbuf, kpb, vpb, Wp1, bp1, Wp2, bp2, Wo, bo, outf);
}

// Round 18
// 423.588 us; speedup vs baseline: 1.1439x; 1.0576x over previous
//
#include <hip/hip_runtime.h>
#include <math.h>

namespace {

constexpr int B  = 2;
constexpr int N  = 1024;
constexpr int CF = 64;    // C_FEAT
constexpr int S  = 512;
constexpr int K  = 32;
constexpr int DM = 128;   // D_MODEL
constexpr int NH = 4;
constexpr int DH = 32;
constexpr int GC = 67;    // grouped channels = CF + 3
constexpr int DIN = 131;  // GC + CF
constexpr int DPAD = 132; // padded row for float4 LDS reads
constexpr int EPAD = 516; // S+4: keeps e rows 16B-aligned for float4 reads

typedef float f2 __attribute__((ext_vector_type(2)));

__device__ inline float max3f(float a, float b, float c) { return fmaxf(fmaxf(a, b), c); }
__device__ inline unsigned min3u(unsigned a, unsigned b, unsigned c) { return min(min(a, b), c); }

// DPP helpers. Reduce-to-lane63 pattern: row_shr:1/2/4/8, row_bcast:15, row_bcast:31.
template <int CTRL>
__device__ inline float dpp_mov_f(float v) {
  // bound_ctrl=true: invalid lanes read 0 — valid identity for fmax of nonneg values.
  return __int_as_float(__builtin_amdgcn_update_dpp(0, __float_as_int(v), CTRL, 0xF, 0xF, true));
}
template <int CTRL>
__device__ inline unsigned dpp_mov_self_u(unsigned v) {
  // bound_ctrl=false with old=v: invalid lanes yield v — identity for min.
  return (unsigned)__builtin_amdgcn_update_dpp((int)v, (int)v, CTRL, 0xF, 0xF, false);
}

// ---------------- FPS (r10 exact): single wave per batch, pk-f32 update, two-pass DPP argmax ----------------
__global__ void __launch_bounds__(64, 1)
fps_kernel(const float* __restrict__ xyz, int* __restrict__ fps_idx,
           float* __restrict__ new_xyz) {
  const int b = blockIdx.x;
  const int lane = threadIdx.x;           // 64 threads = 1 wave
  __shared__ __align__(16) float4 pts4[N];
  __shared__ int farhist[S];
  for (int p = lane; p < N; p += 64) {
    pts4[p] = make_float4(xyz[b*N*3 + p*3+0], xyz[b*N*3 + p*3+1], xyz[b*N*3 + p*3+2], 0.0f);
  }
  __syncthreads();
  f2 X[8], Y[8], Z[8];
  float dist[16];
  #pragma unroll
  for (int j = 0; j < 8; ++j) {
    const float4 a = pts4[(2*j)*64 + lane];
    const float4 c = pts4[(2*j+1)*64 + lane];
    X[j] = f2{a.x, c.x}; Y[j] = f2{a.y, c.y}; Z[j] = f2{a.z, c.z};
  }
  #pragma unroll
  for (int k = 0; k < 16; ++k) dist[k] = 1e10f;
  int far = 0;
  for (int s = 0; s < S; ++s) {
    if (lane == 0) farhist[s] = far;
    const float4 c = pts4[far];
    const f2 cx = f2{c.x, c.x}, cy = f2{c.y, c.y}, cz = f2{c.z, c.z};
    #pragma unroll
    for (int j = 0; j < 8; ++j) {
      const f2 dx = X[j] - cx, dy = Y[j] - cy, dz = Z[j] - cz;
      const f2 q = dx*dx + dy*dy + dz*dz;    // same per-element expression as reference
      dist[2*j]   = fminf(dist[2*j],   q.x);
      dist[2*j+1] = fminf(dist[2*j+1], q.y);
    }
    const float l0 = max3f(dist[0],  dist[1],  dist[2]);
    const float l1 = max3f(dist[3],  dist[4],  dist[5]);
    const float l2 = max3f(dist[6],  dist[7],  dist[8]);
    const float l3 = max3f(dist[9],  dist[10], dist[11]);
    const float l4 = max3f(dist[12], dist[13], dist[14]);
    float mv = fmaxf(max3f(l0, l1, l2), max3f(l3, l4, dist[15]));
    mv = fmaxf(mv, dpp_mov_f<0x111>(mv));
    mv = fmaxf(mv, dpp_mov_f<0x112>(mv));
    mv = fmaxf(mv, dpp_mov_f<0x114>(mv));
    mv = fmaxf(mv, dpp_mov_f<0x118>(mv));
    mv = fmaxf(mv, dpp_mov_f<0x142>(mv));
    mv = fmaxf(mv, dpp_mov_f<0x143>(mv));
    const float maxv = __int_as_float(__builtin_amdgcn_readlane(__float_as_int(mv), 63));
    unsigned cnd[16];
    #pragma unroll
    for (int k = 0; k < 16; ++k) {
      cnd[k] = (dist[k] == maxv) ? (unsigned)(k*64 + lane) : 0xFFFFFFFFu;
    }
    const unsigned u0 = min3u(cnd[0],  cnd[1],  cnd[2]);
    const unsigned u1 = min3u(cnd[3],  cnd[4],  cnd[5]);
    const unsigned u2 = min3u(cnd[6],  cnd[7],  cnd[8]);
    const unsigned u3 = min3u(cnd[9],  cnd[10], cnd[11]);
    const unsigned u4 = min3u(cnd[12], cnd[13], cnd[14]);
    unsigned cand = min(min3u(u0, u1, u2), min3u(u3, u4, cnd[15]));
    cand = min(cand, dpp_mov_self_u<0x111>(cand));
    cand = min(cand, dpp_mov_self_u<0x112>(cand));
    cand = min(cand, dpp_mov_self_u<0x114>(cand));
    cand = min(cand, dpp_mov_self_u<0x118>(cand));
    cand = min(cand, dpp_mov_self_u<0x142>(cand));
    cand = min(cand, dpp_mov_self_u<0x143>(cand));
    far = __builtin_amdgcn_readlane((int)cand, 63);
  }
  __syncthreads();
  for (int s = lane; s < S; s += 64) {
    const int f = farhist[s];
    const float4 c = pts4[f];
    fps_idx[b*S+s] = f;
    new_xyz[(b*S+s)*3+0] = c.x;
    new_xyz[(b*S+s)*3+1] = c.y;
    new_xyz[(b*S+s)*3+2] = c.z;
  }
}

// ---------------- KNN (K=32 of N=1024) + fused per-query group stats (r14) ----------------
__global__ void knn_kernel(const float* __restrict__ xyz, const float* __restrict__ feats,
                           const float* __restrict__ new_xyz, int* __restrict__ knn_idx,
                           float* __restrict__ mean_out, float2* __restrict__ partials) {
  const int b = blockIdx.y;
  const int tid = threadIdx.x;            // 256
  const int wave = tid >> 6, lane = tid & 63;
  const int s = blockIdx.x * 4 + wave;
  __shared__ float pts[N*3];
  __shared__ int sidx_s[4][K];
  for (int i = tid; i < N*3; i += 256) pts[i] = xyz[b*N*3 + i];
  __syncthreads();
  const float qx = new_xyz[(b*S+s)*3+0], qy = new_xyz[(b*S+s)*3+1], qz = new_xyz[(b*S+s)*3+2];
  const float qn = qx*qx + qy*qy + qz*qz;
  float d[16];
  #pragma unroll
  for (int j = 0; j < 16; ++j) {
    const int p = j*64 + lane;
    const float px = pts[p*3+0], py = pts[p*3+1], pz = pts[p*3+2];
    const float dot = qx*px + qy*py + qz*pz;
    const float pn  = px*px + py*py + pz*pz;
    d[j] = (-2.0f*dot + qn) + pn;          // reference's expanded form + add order
  }
  unsigned mask = 0xFFFFu;
  for (int k = 0; k < K; ++k) {
    float bv = INFINITY; int bj = 0;
    #pragma unroll
    for (int j = 0; j < 16; ++j) {
      if (((mask >> j) & 1u) && d[j] < bv) { bv = d[j]; bj = j; }
    }
    int bp = bj*64 + lane;
    #pragma unroll
    for (int m = 1; m < 64; m <<= 1) {
      const float ov = __shfl_xor(bv, m);
      const int   op = __shfl_xor(bp, m);
      if (ov < bv || (ov == bv && op < bp)) { bv = ov; bp = op; }
    }
    if (lane == 0) { knn_idx[(b*S+s)*K + k] = bp; sidx_s[wave][k] = bp; }
    if ((bp & 63) == lane) mask &= ~(1u << (bp >> 6));
  }
  const int bs = b*S + s;
  float ls = 0.0f, lsq = 0.0f;
  float v[K];
  {
    const int c = lane;                    // channels 0..63 (< GC)
    float sum = 0.0f;
    #pragma unroll
    for (int k = 0; k < K; ++k) {
      const int p = sidx_s[wave][k];
      const float g = feats[(b*N+p)*CF + c];
      v[k] = g; sum += g;
    }
    const float mean = sum * (1.0f/K);
    mean_out[bs*GC + c] = mean;
    #pragma unroll
    for (int k = 0; k < K; ++k) {
      const float cc = v[k] - mean;
      ls += cc; lsq += cc*cc;
    }
  }
  if (lane < 3) {                          // channels 64..66 (xyz)
    const int c = CF + lane;
    float sum = 0.0f;
    #pragma unroll
    for (int k = 0; k < K; ++k) {
      const int p = sidx_s[wave][k];
      const float g = xyz[(b*N+p)*3 + lane];
      v[k] = g; sum += g;
    }
    const float mean = sum * (1.0f/K);
    mean_out[bs*GC + c] = mean;
    #pragma unroll
    for (int k = 0; k < K; ++k) {
      const float cc = v[k] - mean;
      ls += cc; lsq += cc*cc;
    }
  }
  #pragma unroll
  for (int m = 1; m < 64; m <<= 1) { ls += __shfl_xor(ls, m); lsq += __shfl_xor(lsq, m); }
  if (lane == 0) partials[bs] = make_float2(ls, lsq);
}

// ---------------- deterministic batch std (ddof=1), 64-lane double butterfly ----------------
__global__ void stats_kernel(const float2* __restrict__ partials, float* __restrict__ invstd) {
  const int b = blockIdx.x;
  const int lane = threadIdx.x;           // 64
  double su = 0.0, sq = 0.0;
  for (int i = lane; i < S; i += 64) {
    const float2 p = partials[b*S+i];
    su += (double)p.x; sq += (double)p.y;
  }
  #pragma unroll
  for (int m = 1; m < 64; m <<= 1) { su += __shfl_xor(su, m); sq += __shfl_xor(sq, m); }
  if (lane == 0) {
    const double nn = (double)S * K * GC;
    const double var = (sq - su*su/nn) / (nn - 1.0);
    invstd[b] = 1.0f / ((float)sqrt(var) + 1e-5f);
  }
}

// ---------------- transfer (r10 scalar acc) + fused k/v projections ----------------
__global__ void transfer_kernel(const float* __restrict__ feats, const float* __restrict__ xyz,
                                const int* __restrict__ knn_idx, const int* __restrict__ fps_idx,
                                const float* __restrict__ mean_in, const float* __restrict__ invstd,
                                const float* __restrict__ alpha, const float* __restrict__ beta,
                                const float* __restrict__ W_t, const float* __restrict__ b_t,
                                const float* __restrict__ bn_g, const float* __restrict__ bn_b,
                                const float* __restrict__ Wk, const float* __restrict__ bk,
                                const float* __restrict__ Wv, const float* __restrict__ bv,
                                float* __restrict__ v_k, float* __restrict__ kpb,
                                float* __restrict__ vpb) {
  const int bs = blockIdx.x;
  const int b = bs / S;
  const int t = threadIdx.x;              // 128
  __shared__ __align__(16) float np_s[K][DPAD];
  __shared__ float vrow[DM];
  __shared__ int sidx[K];
  __shared__ int sanchor;
  if (t < K) sidx[t] = knn_idx[bs*K + t];
  if (t == 0) sanchor = fps_idx[bs];
  __syncthreads();
  const float sinv = invstd[b];
  for (int k = 0; k < K; ++k) {
    const int p = sidx[k];
    for (int c = t; c < DPAD; c += 128) {
      float val = 0.0f;
      if (c < GC) {
        const float g = (c < CF) ? feats[(b*N+p)*CF + c] : xyz[(b*N+p)*3 + (c-CF)];
        val = (g - mean_in[bs*GC + c]) * sinv * alpha[c] + beta[c];
      } else if (c < DIN) {
        val = feats[(b*N+sanchor)*CF + (c - GC)];  // anchor feats, not normalized
      }
      np_s[k][c] = val;
    }
  }
  __syncthreads();
  float acc[K];
  const float bt = b_t[t];
  #pragma unroll
  for (int k = 0; k < K; ++k) acc[k] = bt;
  for (int d4 = 0; d4 < DPAD/4; ++d4) {
    const int d = d4*4;
    const float w0 = W_t[(d+0)*DM + t];
    const float w1 = W_t[(d+1)*DM + t];
    const float w2 = W_t[(d+2)*DM + t];
    const float w3 = (d+3 < DIN) ? W_t[(d+3)*DM + t] : 0.0f;
    #pragma unroll
    for (int k = 0; k < K; ++k) {
      const float4 f = *reinterpret_cast<const float4*>(&np_s[k][d]);
      acc[k] = acc[k] + f.x*w0 + f.y*w1 + f.z*w2 + f.w*w3;
    }
  }
  const float scale = bn_g[t] / sqrtf(1.0f + 1e-5f);
  const float shift = bn_b[t];
  float mx = -INFINITY;
  #pragma unroll
  for (int k = 0; k < K; ++k) {
    const float y = fmaxf(acc[k]*scale + shift, 0.0f);
    mx = fmaxf(mx, y);
  }
  v_k[bs*DM + t] = mx;
  vrow[t] = mx;
  __syncthreads();
  float acck = bk[t], accv = bv[t];
  for (int d = 0; d < DM; ++d) {
    const float f = vrow[d];
    acck += f * Wk[d*DM + t];
    accv += f * Wv[d*DM + t];
  }
  kpb[bs*DM + t] = acck;
  vpb[bs*DM + t] = accv;
}

// ---------------- 3-NN inverse-distance interpolation + fused q projection ----------------
__global__ void interp_kernel(const float* __restrict__ xyz, const float* __restrict__ new_xyz,
                              const float* __restrict__ v_k, const float* __restrict__ Wq,
                              const float* __restrict__ bq, float* __restrict__ qbuf) {
  const int b = blockIdx.y;
  const int tid = threadIdx.x;            // 256
  const int wave = tid >> 6, lane = tid & 63;
  const int n = blockIdx.x*4 + wave;
  __shared__ float pts[S*3];
  __shared__ float vqs[4][DM];
  for (int i = tid; i < S*3; i += 256) pts[i] = new_xyz[b*S*3 + i];
  __syncthreads();
  const float qx = xyz[(b*N+n)*3+0], qy = xyz[(b*N+n)*3+1], qz = xyz[(b*N+n)*3+2];
  const float qn = qx*qx + qy*qy + qz*qz;
  float d[8];
  #pragma unroll
  for (int j = 0; j < 8; ++j) {
    const int p = j*64 + lane;
    const float px = pts[p*3+0], py = pts[p*3+1], pz = pts[p*3+2];
    const float dot = qx*px + qy*py + qz*pz;
    const float pn  = px*px + py*py + pz*pz;
    d[j] = (-2.0f*dot + qn) + pn;
  }
  unsigned mask = 0xFFu;
  float sd[3]; int sp[3];
  #pragma unroll
  for (int k = 0; k < 3; ++k) {
    float bv = INFINITY; int bj = 0;
    #pragma unroll
    for (int j = 0; j < 8; ++j) {
      if (((mask >> j) & 1u) && d[j] < bv) { bv = d[j]; bj = j; }
    }
    int bp = bj*64 + lane;
    #pragma unroll
    for (int m = 1; m < 64; m <<= 1) {
      const float ov = __shfl_xor(bv, m);
      const int   op = __shfl_xor(bp, m);
      if (ov < bv || (ov == bv && op < bp)) { bv = ov; bp = op; }
    }
    sd[k] = bv; sp[k] = bp;
    if ((bp & 63) == lane) mask &= ~(1u << (bp >> 6));
  }
  float w0 = 1.0f / fmaxf(sd[0], 1e-10f);
  float w1 = 1.0f / fmaxf(sd[1], 1e-10f);
  float w2 = 1.0f / fmaxf(sd[2], 1e-10f);
  const float wsum = w0 + w1 + w2;
  w0 /= wsum; w1 /= wsum; w2 /= wsum;
  const float* vk0 = v_k + (b*S + sp[0])*DM;
  const float* vk1 = v_k + (b*S + sp[1])*DM;
  const float* vk2 = v_k + (b*S + sp[2])*DM;
  #pragma unroll
  for (int c = lane; c < DM; c += 64) {
    vqs[wave][c] = w0*vk0[c] + w1*vk1[c] + w2*vk2[c];
  }
  __syncthreads();
  const float* row = vqs[wave];
  #pragma unroll
  for (int half = 0; half < 2; ++half) {
    const int c = lane + half*64;
    float acc = bq[c];
    for (int d = 0; d < DM; ++d) acc += row[d] * Wq[d*DM + c];
    qbuf[(b*N+n)*DM + c] = acc;
  }
}

// ---------------- cross-attention: 512 threads, one j-column per thread ----------------
// r17 diagnosis: attn was wave-starved (2 waves/block, 4 waves/SIMD, each thread
// serially owning 4 j-columns of the ~1.3K-VALU RPE chain). Now 8 waves/block,
// each thread owns ONE j-column: 4x less serial work/thread, 2x waves/SIMD.
// Softmax phase unchanged (bit-identical). PV split into 4 fixed-order partials
// (reassociation only, ~1e-6 drift vs 0.1 tolerance).
__global__ void attn_kernel(const float* __restrict__ xyz, const float* __restrict__ new_xyz,
                            const float* __restrict__ qb, const float* __restrict__ kp,
                            const float* __restrict__ vp, const float* __restrict__ Wp1,
                            const float* __restrict__ bp1, const float* __restrict__ Wp2,
                            const float* __restrict__ bp2, const float* __restrict__ Wo,
                            const float* __restrict__ bo, float* __restrict__ out) {
  const int bn = blockIdx.x;              // b*N + n
  const int b = bn / N;
  const int t = threadIdx.x;              // 512
  __shared__ __align__(16) float e[NH][EPAD];
  __shared__ float qn_s[DM];
  __shared__ __align__(16) float oa4[4][DM];
  __shared__ float ssum[NH];
  if (t < DM) qn_s[t] = qb[bn*DM + t];
  __syncthreads();
  const float qx = xyz[bn*3+0], qy = xyz[bn*3+1], qz = xyz[bn*3+2];
  const float rs = 0.17677669529663687f;  // 1/sqrt(32)
  // phase 1: each thread computes e[*][j] for its single column j = t
  {
    const int j = t;
    const float px = new_xyz[(b*S+j)*3+0], py = new_xyz[(b*S+j)*3+1], pz = new_xyz[(b*S+j)*3+2];
    const float rx = qx-px, ry = qy-py, rz = qz-pz;
    float r0 = bp2[0], r1 = bp2[1], r2 = bp2[2], r3 = bp2[3];
    for (int m = 0; m < DM; ++m) {
      float hm = rx*Wp1[m] + ry*Wp1[DM+m] + rz*Wp1[2*DM+m] + bp1[m];
      hm = fmaxf(hm, 0.0f);
      r0 += hm*Wp2[m*NH+0]; r1 += hm*Wp2[m*NH+1];
      r2 += hm*Wp2[m*NH+2]; r3 += hm*Wp2[m*NH+3];
    }
    const float rpe[NH] = {r0, r1, r2, r3};
    #pragma unroll
    for (int h = 0; h < NH; ++h) {
      const float4* kr4 = reinterpret_cast<const float4*>(kp + (b*S+j)*DM + h*DH);
      const float* qr = qn_s + h*DH;
      float acc = 0.0f;
      #pragma unroll
      for (int dd = 0; dd < 8; ++dd) {
        const float4 kv = kr4[dd];
        acc += qr[dd*4+0]*kv.x + qr[dd*4+1]*kv.y + qr[dd*4+2]*kv.z + qr[dd*4+3]*kv.w;
      }
      e[h][j] = acc*rs + rpe[h];
    }
  }
  __syncthreads();
  // phase 2: per-head softmax (threads 0..127; unchanged reduction order)
  if (t < 128) {
    const int h = t >> 5, g = t & 31;     // 32 threads per head
    float mx = -INFINITY;
    for (int j = g; j < S; j += 32) mx = fmaxf(mx, e[h][j]);
    #pragma unroll
    for (int m = 16; m >= 1; m >>= 1) mx = fmaxf(mx, __shfl_xor(mx, m));
    float sum = 0.0f;
    for (int j = g; j < S; j += 32) { const float ex = expf(e[h][j]-mx); e[h][j] = ex; sum += ex; }
    #pragma unroll
    for (int m = 16; m >= 1; m >>= 1) sum += __shfl_xor(sum, m);
    if (g == 0) ssum[h] = sum;
  }
  __syncthreads();
  // phase 3: PV split over 4 groups of 128 threads, 128 j's each
  {
    const int grp = t >> 7;               // 0..3
    const int tt = t & 127;               // output channel
    const int h = tt >> 5;
    float acc = 0.0f;
    const int j0 = grp*128;
    for (int j = j0; j < j0 + 128; j += 4) {
      const float4 ev = *reinterpret_cast<const float4*>(&e[h][j]);
      acc += ev.x * vp[(b*S+j+0)*DM + tt];
      acc += ev.y * vp[(b*S+j+1)*DM + tt];
      acc += ev.z * vp[(b*S+j+2)*DM + tt];
      acc += ev.w * vp[(b*S+j+3)*DM + tt];
    }
    oa4[grp][tt] = acc;
  }
  __syncthreads();
  if (t < 128) {
    const int h = t >> 5;
    const float total = ((oa4[0][t] + oa4[1][t]) + oa4[2][t]) + oa4[3][t];
    oa4[0][t] = total / ssum[h];
  }
  __syncthreads();
  // phase 4: output projection (threads 0..127)
  if (t < 128) {
    float facc = bo[t];
    for (int d = 0; d < DM; ++d) facc += oa4[0][d] * Wo[d*DM + t];
    out[bn*DM + t] = facc;
  }
}

}  // namespace

extern "C" void kernel_launch(void* const* d_in, const int* in_sizes, int n_in,
                              void* d_out, int out_size, void* d_ws, size_t ws_size,
                              hipStream_t stream) {
  const float* xyz   = (const float*)d_in[0];
  const float* feats = (const float*)d_in[1];
  const float* alpha = (const float*)d_in[2];
  const float* beta  = (const float*)d_in[3];
  const float* W_t   = (const float*)d_in[4];
  const float* b_t   = (const float*)d_in[5];
  const float* bn_g  = (const float*)d_in[6];
  const float* bn_b  = (const float*)d_in[7];
  const float* Wq = (const float*)d_in[8];  const float* bq = (const float*)d_in[9];
  const float* Wk = (const float*)d_in[10]; const float* bk = (const float*)d_in[11];
  const float* Wv = (const float*)d_in[12]; const float* bv = (const float*)d_in[13];
  const float* Wo = (const float*)d_in[14]; const float* bo = (const float*)d_in[15];
  const float* Wp1= (const float*)d_in[16]; const float* bp1= (const float*)d_in[17];
  const float* Wp2= (const float*)d_in[18]; const float* bp2= (const float*)d_in[19];

  char* w = (char*)d_ws;
  int*    fps_i = (int*)   (w + 0);        // B*S ints            (4 KB)
  float*  nxyz  = (float*) (w + 4096);     // B*S*3               (12 KB)
  int*    knn_i = (int*)   (w + 16384);    // B*S*K ints          (128 KB)
  float*  meanb = (float*) (w + 147456);   // B*S*GC              (268 KB)
  float2* part  = (float2*)(w + 421888);   // B*S float2          (8 KB)
  float*  invs  = (float*) (w + 430080);   // B floats
  float*  vk    = (float*) (w + 430336);   // B*S*DM              (512 KB)
  float*  qbuf  = (float*) (w + 2003200);  // B*N*DM              (1 MB)
  float*  kpb   = (float*) (w + 3051776);  // B*S*DM              (512 KB)
  float*  vpb   = (float*) (w + 3576064);  // B*S*DM              (512 KB)
  float*  outf  = (float*)d_out;

  fps_kernel<<<B, 64, 0, stream>>>(xyz, fps_i, nxyz);
  knn_kernel<<<dim3(S/4, B), 256, 0, stream>>>(xyz, feats, nxyz, knn_i, meanb, part);
  stats_kernel<<<B, 64, 0, stream>>>(part, invs);
  transfer_kernel<<<B*S, 128, 0, stream>>>(feats, xyz, knn_i, fps_i, meanb, invs,
                                           alpha, beta, W_t, b_t, bn_g, bn_b,
                                           Wk, bk, Wv, bv, vk, kpb, vpb);
  interp_kernel<<<dim3(N/4, B), 256, 0, stream>>>(xyz, nxyz, vk, Wq, bq, qbuf);
  attn_kernel<<<B*N, 512, 0, stream>>>(xyz, nxyz, qbuf, kpb, vpb, Wp1, bp1, Wp2, bp2, Wo, bo, outf);
}

// Round 19
// 381.119 us; speedup vs baseline: 1.2713x; 1.1114x over previous
//
#include <hip/hip_runtime.h>
#include <math.h>

namespace {

constexpr int B  = 2;
constexpr int N  = 1024;
constexpr int CF = 64;    // C_FEAT
constexpr int S  = 512;
constexpr int K  = 32;
constexpr int DM = 128;   // D_MODEL
constexpr int NH = 4;
constexpr int DH = 32;
constexpr int GC = 67;    // grouped channels = CF + 3
constexpr int DIN = 131;  // GC + CF
constexpr int DPAD = 132; // padded row for float4 LDS reads
constexpr int EPAD = 516; // S+4: keeps e rows 16B-aligned for float4 reads
constexpr int QB = 4;     // queries per attn block

typedef float f2 __attribute__((ext_vector_type(2)));

__device__ inline float max3f(float a, float b, float c) { return fmaxf(fmaxf(a, b), c); }
__device__ inline unsigned min3u(unsigned a, unsigned b, unsigned c) { return min(min(a, b), c); }

// DPP helpers. Reduce-to-lane63 pattern: row_shr:1/2/4/8, row_bcast:15, row_bcast:31.
template <int CTRL>
__device__ inline float dpp_mov_f(float v) {
  // bound_ctrl=true: invalid lanes read 0 — valid identity for fmax of nonneg values.
  return __int_as_float(__builtin_amdgcn_update_dpp(0, __float_as_int(v), CTRL, 0xF, 0xF, true));
}
template <int CTRL>
__device__ inline unsigned dpp_mov_self_u(unsigned v) {
  // bound_ctrl=false with old=v: invalid lanes yield v — identity for min.
  return (unsigned)__builtin_amdgcn_update_dpp((int)v, (int)v, CTRL, 0xF, 0xF, false);
}

// ---------------- FPS (r10 exact): single wave per batch, pk-f32 update, two-pass DPP argmax ----------------
__global__ void __launch_bounds__(64, 1)
fps_kernel(const float* __restrict__ xyz, int* __restrict__ fps_idx,
           float* __restrict__ new_xyz) {
  const int b = blockIdx.x;
  const int lane = threadIdx.x;           // 64 threads = 1 wave
  __shared__ __align__(16) float4 pts4[N];
  __shared__ int farhist[S];
  for (int p = lane; p < N; p += 64) {
    pts4[p] = make_float4(xyz[b*N*3 + p*3+0], xyz[b*N*3 + p*3+1], xyz[b*N*3 + p*3+2], 0.0f);
  }
  __syncthreads();
  f2 X[8], Y[8], Z[8];
  float dist[16];
  #pragma unroll
  for (int j = 0; j < 8; ++j) {
    const float4 a = pts4[(2*j)*64 + lane];
    const float4 c = pts4[(2*j+1)*64 + lane];
    X[j] = f2{a.x, c.x}; Y[j] = f2{a.y, c.y}; Z[j] = f2{a.z, c.z};
  }
  #pragma unroll
  for (int k = 0; k < 16; ++k) dist[k] = 1e10f;
  int far = 0;
  for (int s = 0; s < S; ++s) {
    if (lane == 0) farhist[s] = far;
    const float4 c = pts4[far];
    const f2 cx = f2{c.x, c.x}, cy = f2{c.y, c.y}, cz = f2{c.z, c.z};
    #pragma unroll
    for (int j = 0; j < 8; ++j) {
      const f2 dx = X[j] - cx, dy = Y[j] - cy, dz = Z[j] - cz;
      const f2 q = dx*dx + dy*dy + dz*dz;    // same per-element expression as reference
      dist[2*j]   = fminf(dist[2*j],   q.x);
      dist[2*j+1] = fminf(dist[2*j+1], q.y);
    }
    const float l0 = max3f(dist[0],  dist[1],  dist[2]);
    const float l1 = max3f(dist[3],  dist[4],  dist[5]);
    const float l2 = max3f(dist[6],  dist[7],  dist[8]);
    const float l3 = max3f(dist[9],  dist[10], dist[11]);
    const float l4 = max3f(dist[12], dist[13], dist[14]);
    float mv = fmaxf(max3f(l0, l1, l2), max3f(l3, l4, dist[15]));
    mv = fmaxf(mv, dpp_mov_f<0x111>(mv));
    mv = fmaxf(mv, dpp_mov_f<0x112>(mv));
    mv = fmaxf(mv, dpp_mov_f<0x114>(mv));
    mv = fmaxf(mv, dpp_mov_f<0x118>(mv));
    mv = fmaxf(mv, dpp_mov_f<0x142>(mv));
    mv = fmaxf(mv, dpp_mov_f<0x143>(mv));
    const float maxv = __int_as_float(__builtin_amdgcn_readlane(__float_as_int(mv), 63));
    unsigned cnd[16];
    #pragma unroll
    for (int k = 0; k < 16; ++k) {
      cnd[k] = (dist[k] == maxv) ? (unsigned)(k*64 + lane) : 0xFFFFFFFFu;
    }
    const unsigned u0 = min3u(cnd[0],  cnd[1],  cnd[2]);
    const unsigned u1 = min3u(cnd[3],  cnd[4],  cnd[5]);
    const unsigned u2 = min3u(cnd[6],  cnd[7],  cnd[8]);
    const unsigned u3 = min3u(cnd[9],  cnd[10], cnd[11]);
    const unsigned u4 = min3u(cnd[12], cnd[13], cnd[14]);
    unsigned cand = min(min3u(u0, u1, u2), min3u(u3, u4, cnd[15]));
    cand = min(cand, dpp_mov_self_u<0x111>(cand));
    cand = min(cand, dpp_mov_self_u<0x112>(cand));
    cand = min(cand, dpp_mov_self_u<0x114>(cand));
    cand = min(cand, dpp_mov_self_u<0x118>(cand));
    cand = min(cand, dpp_mov_self_u<0x142>(cand));
    cand = min(cand, dpp_mov_self_u<0x143>(cand));
    far = __builtin_amdgcn_readlane((int)cand, 63);
  }
  __syncthreads();
  for (int s = lane; s < S; s += 64) {
    const int f = farhist[s];
    const float4 c = pts4[f];
    fps_idx[b*S+s] = f;
    new_xyz[(b*S+s)*3+0] = c.x;
    new_xyz[(b*S+s)*3+1] = c.y;
    new_xyz[(b*S+s)*3+2] = c.z;
  }
}

// ---------------- KNN (K=32 of N=1024) + fused per-query group stats (r14) ----------------
__global__ void knn_kernel(const float* __restrict__ xyz, const float* __restrict__ feats,
                           const float* __restrict__ new_xyz, int* __restrict__ knn_idx,
                           float* __restrict__ mean_out, float2* __restrict__ partials) {
  const int b = blockIdx.y;
  const int tid = threadIdx.x;            // 256
  const int wave = tid >> 6, lane = tid & 63;
  const int s = blockIdx.x * 4 + wave;
  __shared__ float pts[N*3];
  __shared__ int sidx_s[4][K];
  for (int i = tid; i < N*3; i += 256) pts[i] = xyz[b*N*3 + i];
  __syncthreads();
  const float qx = new_xyz[(b*S+s)*3+0], qy = new_xyz[(b*S+s)*3+1], qz = new_xyz[(b*S+s)*3+2];
  const float qn = qx*qx + qy*qy + qz*qz;
  float d[16];
  #pragma unroll
  for (int j = 0; j < 16; ++j) {
    const int p = j*64 + lane;
    const float px = pts[p*3+0], py = pts[p*3+1], pz = pts[p*3+2];
    const float dot = qx*px + qy*py + qz*pz;
    const float pn  = px*px + py*py + pz*pz;
    d[j] = (-2.0f*dot + qn) + pn;          // reference's expanded form + add order
  }
  unsigned mask = 0xFFFFu;
  for (int k = 0; k < K; ++k) {
    float bv = INFINITY; int bj = 0;
    #pragma unroll
    for (int j = 0; j < 16; ++j) {
      if (((mask >> j) & 1u) && d[j] < bv) { bv = d[j]; bj = j; }
    }
    int bp = bj*64 + lane;
    #pragma unroll
    for (int m = 1; m < 64; m <<= 1) {
      const float ov = __shfl_xor(bv, m);
      const int   op = __shfl_xor(bp, m);
      if (ov < bv || (ov == bv && op < bp)) { bv = ov; bp = op; }
    }
    if (lane == 0) { knn_idx[(b*S+s)*K + k] = bp; sidx_s[wave][k] = bp; }
    if ((bp & 63) == lane) mask &= ~(1u << (bp >> 6));
  }
  const int bs = b*S + s;
  float ls = 0.0f, lsq = 0.0f;
  float v[K];
  {
    const int c = lane;                    // channels 0..63 (< GC)
    float sum = 0.0f;
    #pragma unroll
    for (int k = 0; k < K; ++k) {
      const int p = sidx_s[wave][k];
      const float g = feats[(b*N+p)*CF + c];
      v[k] = g; sum += g;
    }
    const float mean = sum * (1.0f/K);
    mean_out[bs*GC + c] = mean;
    #pragma unroll
    for (int k = 0; k < K; ++k) {
      const float cc = v[k] - mean;
      ls += cc; lsq += cc*cc;
    }
  }
  if (lane < 3) {                          // channels 64..66 (xyz)
    const int c = CF + lane;
    float sum = 0.0f;
    #pragma unroll
    for (int k = 0; k < K; ++k) {
      const int p = sidx_s[wave][k];
      const float g = xyz[(b*N+p)*3 + lane];
      v[k] = g; sum += g;
    }
    const float mean = sum * (1.0f/K);
    mean_out[bs*GC + c] = mean;
    #pragma unroll
    for (int k = 0; k < K; ++k) {
      const float cc = v[k] - mean;
      ls += cc; lsq += cc*cc;
    }
  }
  #pragma unroll
  for (int m = 1; m < 64; m <<= 1) { ls += __shfl_xor(ls, m); lsq += __shfl_xor(lsq, m); }
  if (lane == 0) partials[bs] = make_float2(ls, lsq);
}

// ---------------- deterministic batch std (ddof=1), 64-lane double butterfly ----------------
__global__ void stats_kernel(const float2* __restrict__ partials, float* __restrict__ invstd) {
  const int b = blockIdx.x;
  const int lane = threadIdx.x;           // 64
  double su = 0.0, sq = 0.0;
  for (int i = lane; i < S; i += 64) {
    const float2 p = partials[b*S+i];
    su += (double)p.x; sq += (double)p.y;
  }
  #pragma unroll
  for (int m = 1; m < 64; m <<= 1) { su += __shfl_xor(su, m); sq += __shfl_xor(sq, m); }
  if (lane == 0) {
    const double nn = (double)S * K * GC;
    const double var = (sq - su*su/nn) / (nn - 1.0);
    invstd[b] = 1.0f / ((float)sqrt(var) + 1e-5f);
  }
}

// ---------------- transfer (r10 scalar acc) + fused k/v projections ----------------
__global__ void transfer_kernel(const float* __restrict__ feats, const float* __restrict__ xyz,
                                const int* __restrict__ knn_idx, const int* __restrict__ fps_idx,
                                const float* __restrict__ mean_in, const float* __restrict__ invstd,
                                const float* __restrict__ alpha, const float* __restrict__ beta,
                                const float* __restrict__ W_t, const float* __restrict__ b_t,
                                const float* __restrict__ bn_g, const float* __restrict__ bn_b,
                                const float* __restrict__ Wk, const float* __restrict__ bk,
                                const float* __restrict__ Wv, const float* __restrict__ bv,
                                float* __restrict__ v_k, float* __restrict__ kpb,
                                float* __restrict__ vpb) {
  const int bs = blockIdx.x;
  const int b = bs / S;
  const int t = threadIdx.x;              // 128
  __shared__ __align__(16) float np_s[K][DPAD];
  __shared__ float vrow[DM];
  __shared__ int sidx[K];
  __shared__ int sanchor;
  if (t < K) sidx[t] = knn_idx[bs*K + t];
  if (t == 0) sanchor = fps_idx[bs];
  __syncthreads();
  const float sinv = invstd[b];
  for (int k = 0; k < K; ++k) {
    const int p = sidx[k];
    for (int c = t; c < DPAD; c += 128) {
      float val = 0.0f;
      if (c < GC) {
        const float g = (c < CF) ? feats[(b*N+p)*CF + c] : xyz[(b*N+p)*3 + (c-CF)];
        val = (g - mean_in[bs*GC + c]) * sinv * alpha[c] + beta[c];
      } else if (c < DIN) {
        val = feats[(b*N+sanchor)*CF + (c - GC)];  // anchor feats, not normalized
      }
      np_s[k][c] = val;
    }
  }
  __syncthreads();
  float acc[K];
  const float bt = b_t[t];
  #pragma unroll
  for (int k = 0; k < K; ++k) acc[k] = bt;
  for (int d4 = 0; d4 < DPAD/4; ++d4) {
    const int d = d4*4;
    const float w0 = W_t[(d+0)*DM + t];
    const float w1 = W_t[(d+1)*DM + t];
    const float w2 = W_t[(d+2)*DM + t];
    const float w3 = (d+3 < DIN) ? W_t[(d+3)*DM + t] : 0.0f;
    #pragma unroll
    for (int k = 0; k < K; ++k) {
      const float4 f = *reinterpret_cast<const float4*>(&np_s[k][d]);
      acc[k] = acc[k] + f.x*w0 + f.y*w1 + f.z*w2 + f.w*w3;
    }
  }
  const float scale = bn_g[t] / sqrtf(1.0f + 1e-5f);
  const float shift = bn_b[t];
  float mx = -INFINITY;
  #pragma unroll
  for (int k = 0; k < K; ++k) {
    const float y = fmaxf(acc[k]*scale + shift, 0.0f);
    mx = fmaxf(mx, y);
  }
  v_k[bs*DM + t] = mx;
  vrow[t] = mx;
  __syncthreads();
  float acck = bk[t], accv = bv[t];
  for (int d = 0; d < DM; ++d) {
    const float f = vrow[d];
    acck += f * Wk[d*DM + t];
    accv += f * Wv[d*DM + t];
  }
  kpb[bs*DM + t] = acck;
  vpb[bs*DM + t] = accv;
}

// ---------------- 3-NN inverse-distance interpolation + fused q projection ----------------
__global__ void interp_kernel(const float* __restrict__ xyz, const float* __restrict__ new_xyz,
                              const float* __restrict__ v_k, const float* __restrict__ Wq,
                              const float* __restrict__ bq, float* __restrict__ qbuf) {
  const int b = blockIdx.y;
  const int tid = threadIdx.x;            // 256
  const int wave = tid >> 6, lane = tid & 63;
  const int n = blockIdx.x*4 + wave;
  __shared__ float pts[S*3];
  __shared__ float vqs[4][DM];
  for (int i = tid; i < S*3; i += 256) pts[i] = new_xyz[b*S*3 + i];
  __syncthreads();
  const float qx = xyz[(b*N+n)*3+0], qy = xyz[(b*N+n)*3+1], qz = xyz[(b*N+n)*3+2];
  const float qn = qx*qx + qy*qy + qz*qz;
  float d[8];
  #pragma unroll
  for (int j = 0; j < 8; ++j) {
    const int p = j*64 + lane;
    const float px = pts[p*3+0], py = pts[p*3+1], pz = pts[p*3+2];
    const float dot = qx*px + qy*py + qz*pz;
    const float pn  = px*px + py*py + pz*pz;
    d[j] = (-2.0f*dot + qn) + pn;
  }
  unsigned mask = 0xFFu;
  float sd[3]; int sp[3];
  #pragma unroll
  for (int k = 0; k < 3; ++k) {
    float bv = INFINITY; int bj = 0;
    #pragma unroll
    for (int j = 0; j < 8; ++j) {
      if (((mask >> j) & 1u) && d[j] < bv) { bv = d[j]; bj = j; }
    }
    int bp = bj*64 + lane;
    #pragma unroll
    for (int m = 1; m < 64; m <<= 1) {
      const float ov = __shfl_xor(bv, m);
      const int   op = __shfl_xor(bp, m);
      if (ov < bv || (ov == bv && op < bp)) { bv = ov; bp = op; }
    }
    sd[k] = bv; sp[k] = bp;
    if ((bp & 63) == lane) mask &= ~(1u << (bp >> 6));
  }
  float w0 = 1.0f / fmaxf(sd[0], 1e-10f);
  float w1 = 1.0f / fmaxf(sd[1], 1e-10f);
  float w2 = 1.0f / fmaxf(sd[2], 1e-10f);
  const float wsum = w0 + w1 + w2;
  w0 /= wsum; w1 /= wsum; w2 /= wsum;
  const float* vk0 = v_k + (b*S + sp[0])*DM;
  const float* vk1 = v_k + (b*S + sp[1])*DM;
  const float* vk2 = v_k + (b*S + sp[2])*DM;
  #pragma unroll
  for (int c = lane; c < DM; c += 64) {
    vqs[wave][c] = w0*vk0[c] + w1*vk1[c] + w2*vk2[c];
  }
  __syncthreads();
  const float* row = vqs[wave];
  #pragma unroll
  for (int half = 0; half < 2; ++half) {
    const int c = lane + half*64;
    float acc = bq[c];
    for (int d = 0; d < DM; ++d) acc += row[d] * Wq[d*DM + c];
    qbuf[(b*N+n)*DM + c] = acc;
  }
}

// ---------------- cross-attention: 4 queries per block, 512 threads ----------------
// Phase 1: thread t owns column j=t for ALL 4 queries — each uniform weight
// load amortizes over 4 hm chains (stall fraction /4), each kp row float4 is
// reused by 4 q-dots. Phases 2-4: 4 query-groups x 128 threads, each running
// the exact r16 per-query softmax/PV/projection sequence -> bit-identical.
__global__ void attn_kernel(const float* __restrict__ xyz, const float* __restrict__ new_xyz,
                            const float* __restrict__ qb, const float* __restrict__ kp,
                            const float* __restrict__ vp, const float* __restrict__ Wp1,
                            const float* __restrict__ bp1, const float* __restrict__ Wp2,
                            const float* __restrict__ bp2, const float* __restrict__ Wo,
                            const float* __restrict__ bo, float* __restrict__ out) {
  const int bn0 = blockIdx.x * QB;        // first of 4 queries
  const int b = bn0 / N;
  const int t = threadIdx.x;              // 512
  __shared__ __align__(16) float e[QB][NH][EPAD];
  __shared__ __align__(16) float qn_s[QB][DM];
  __shared__ float oa[QB][DM];
  __shared__ float ssum[QB][NH];
  qn_s[t >> 7][t & 127] = qb[(bn0 + (t >> 7))*DM + (t & 127)];
  __syncthreads();
  float qxs[QB], qys[QB], qzs[QB];
  #pragma unroll
  for (int qq = 0; qq < QB; ++qq) {
    qxs[qq] = xyz[(bn0+qq)*3+0];
    qys[qq] = xyz[(bn0+qq)*3+1];
    qzs[qq] = xyz[(bn0+qq)*3+2];
  }
  const float rs = 0.17677669529663687f;  // 1/sqrt(32)
  // phase 1: column j = t, all 4 queries
  {
    const int j = t;
    const float px = new_xyz[(b*S+j)*3+0], py = new_xyz[(b*S+j)*3+1], pz = new_xyz[(b*S+j)*3+2];
    float rx[QB], ry[QB], rz[QB];
    float r0[QB], r1[QB], r2[QB], r3[QB];
    #pragma unroll
    for (int qq = 0; qq < QB; ++qq) {
      rx[qq] = qxs[qq]-px; ry[qq] = qys[qq]-py; rz[qq] = qzs[qq]-pz;
      r0[qq] = bp2[0]; r1[qq] = bp2[1]; r2[qq] = bp2[2]; r3[qq] = bp2[3];
    }
    for (int m = 0; m < DM; ++m) {
      const float w1 = Wp1[m], w2 = Wp1[DM+m], w3 = Wp1[2*DM+m], bb = bp1[m];
      const float p0 = Wp2[m*NH+0], p1 = Wp2[m*NH+1], p2 = Wp2[m*NH+2], p3 = Wp2[m*NH+3];
      #pragma unroll
      for (int qq = 0; qq < QB; ++qq) {
        float hm = rx[qq]*w1 + ry[qq]*w2 + rz[qq]*w3 + bb;
        hm = fmaxf(hm, 0.0f);
        r0[qq] += hm*p0; r1[qq] += hm*p1; r2[qq] += hm*p2; r3[qq] += hm*p3;
      }
    }
    #pragma unroll
    for (int h = 0; h < NH; ++h) {
      const float4* kr4 = reinterpret_cast<const float4*>(kp + (b*S+j)*DM + h*DH);
      float acc[QB];
      #pragma unroll
      for (int qq = 0; qq < QB; ++qq) acc[qq] = 0.0f;
      #pragma unroll
      for (int dd = 0; dd < 8; ++dd) {
        const float4 kv = kr4[dd];
        #pragma unroll
        for (int qq = 0; qq < QB; ++qq) {
          const float* qr = &qn_s[qq][h*DH + dd*4];
          acc[qq] += qr[0]*kv.x + qr[1]*kv.y + qr[2]*kv.z + qr[3]*kv.w;
        }
      }
      e[0][h][j] = acc[0]*rs + ((h==0)?r0[0]:(h==1)?r1[0]:(h==2)?r2[0]:r3[0]);
      e[1][h][j] = acc[1]*rs + ((h==0)?r0[1]:(h==1)?r1[1]:(h==2)?r2[1]:r3[1]);
      e[2][h][j] = acc[2]*rs + ((h==0)?r0[2]:(h==1)?r1[2]:(h==2)?r2[2]:r3[2]);
      e[3][h][j] = acc[3]*rs + ((h==0)?r0[3]:(h==1)?r1[3]:(h==2)?r2[3]:r3[3]);
    }
  }
  __syncthreads();
  // phases 2-4: query-group qq = t>>7, tt = t&127 (exact r16 per-query code)
  const int qq = t >> 7;
  const int tt = t & 127;
  const int h = tt >> 5, g = tt & 31;
  {
    float mx = -INFINITY;
    for (int j = g; j < S; j += 32) mx = fmaxf(mx, e[qq][h][j]);
    #pragma unroll
    for (int m = 16; m >= 1; m >>= 1) mx = fmaxf(mx, __shfl_xor(mx, m));
    float sum = 0.0f;
    for (int j = g; j < S; j += 32) { const float ex = expf(e[qq][h][j]-mx); e[qq][h][j] = ex; sum += ex; }
    #pragma unroll
    for (int m = 16; m >= 1; m >>= 1) sum += __shfl_xor(sum, m);
    if (g == 0) ssum[qq][h] = sum;
  }
  __syncthreads();
  {
    float acc = 0.0f;
    for (int j = 0; j < S; j += 4) {
      const float4 ev = *reinterpret_cast<const float4*>(&e[qq][h][j]);
      acc += ev.x * vp[(b*S+j+0)*DM + tt];
      acc += ev.y * vp[(b*S+j+1)*DM + tt];
      acc += ev.z * vp[(b*S+j+2)*DM + tt];
      acc += ev.w * vp[(b*S+j+3)*DM + tt];
    }
    oa[qq][tt] = acc / ssum[qq][h];
  }
  __syncthreads();
  {
    float facc = bo[tt];
    for (int d = 0; d < DM; ++d) facc += oa[qq][d] * Wo[d*DM + tt];
    out[(bn0+qq)*DM + tt] = facc;
  }
}

}  // namespace

extern "C" void kernel_launch(void* const* d_in, const int* in_sizes, int n_in,
                              void* d_out, int out_size, void* d_ws, size_t ws_size,
                              hipStream_t stream) {
  const float* xyz   = (const float*)d_in[0];
  const float* feats = (const float*)d_in[1];
  const float* alpha = (const float*)d_in[2];
  const float* beta  = (const float*)d_in[3];
  const float* W_t   = (const float*)d_in[4];
  const float* b_t   = (const float*)d_in[5];
  const float* bn_g  = (const float*)d_in[6];
  const float* bn_b  = (const float*)d_in[7];
  const float* Wq = (const float*)d_in[8];  const float* bq = (const float*)d_in[9];
  const float* Wk = (const float*)d_in[10]; const float* bk = (const float*)d_in[11];
  const float* Wv = (const float*)d_in[12]; const float* bv = (const float*)d_in[13];
  const float* Wo = (const float*)d_in[14]; const float* bo = (const float*)d_in[15];
  const float* Wp1= (const float*)d_in[16]; const float* bp1= (const float*)d_in[17];
  const float* Wp2= (const float*)d_in[18]; const float* bp2= (const float*)d_in[19];

  char* w = (char*)d_ws;
  int*    fps_i = (int*)   (w + 0);        // B*S ints            (4 KB)
  float*  nxyz  = (float*) (w + 4096);     // B*S*3               (12 KB)
  int*    knn_i = (int*)   (w + 16384);    // B*S*K ints          (128 KB)
  float*  meanb = (float*) (w + 147456);   // B*S*GC              (268 KB)
  float2* part  = (float2*)(w + 421888);   // B*S float2          (8 KB)
  float*  invs  = (float*) (w + 430080);   // B floats
  float*  vk    = (float*) (w + 430336);   // B*S*DM              (512 KB)
  float*  qbuf  = (float*) (w + 2003200);  // B*N*DM              (1 MB)
  float*  kpb   = (float*) (w + 3051776);  // B*S*DM              (512 KB)
  float*  vpb   = (float*) (w + 3576064);  // B*S*DM              (512 KB)
  float*  outf  = (float*)d_out;

  fps_kernel<<<B, 64, 0, stream>>>(xyz, fps_i, nxyz);
  knn_kernel<<<dim3(S/4, B), 256, 0, stream>>>(xyz, feats, nxyz, knn_i, meanb, part);
  stats_kernel<<<B, 64, 0, stream>>>(part, invs);
  transfer_kernel<<<B*S, 128, 0, stream>>>(feats, xyz, knn_i, fps_i, meanb, invs,
                                           alpha, beta, W_t, b_t, bn_g, bn_b,
                                           Wk, bk, Wv, bv, vk, kpb, vpb);
  interp_kernel<<<dim3(N/4, B), 256, 0, stream>>>(xyz, nxyz, vk, Wq, bq, qbuf);
  attn_kernel<<<(B*N)/QB, 512, 0, stream>>>(xyz, nxyz, qbuf, kpb, vpb, Wp1, bp1, Wp2, bp2, Wo, bo, outf);
}